// Round 1
// baseline (1835.419 us; speedup 1.0000x reference)
//
#include <hip/hip_runtime.h>
#include <math.h>
#include <float.h>
#include <limits.h>

// ---------------- problem constants (fixed by setup_inputs) ----------------
#define HH 1024
#define WW 1024
#define NPIX (HH*WW)          // 1048576
#define RH 1449               // ceil(1024*sqrt(2))
#define RW 1449
#define RA (RH*RW)            // 2099601
#define NBSEG 5000
#define START 211             // int((rot_bbox_w - 1024)/2) for 45 deg
#define NBLK_PIX (NPIX/256)   // 4096

// output layout (floats, concatenated in return order)
#define OUT_XYWH_OFF  0          // 5000*4
#define OUT_SIZE_OFF  20000      // 5000
#define OUT_COLOR_OFF 25000      // 5000*3*25
#define OUT_TEX_OFF   400000     // 5000*3*8*10
#define OUT_TOTAL     1600000

// ---------------- device helpers ----------------

// 3x3 zero-padded cross-correlation with kx=[[-3,0,3],[10,0,10],[-3,0,3]] and kx^T,
// for all 3 channels of a planar image. (XLA conv_general_dilated = cross-correlation.)
__device__ __forceinline__ void scharr3(const float* __restrict__ base, long plane,
                                        int y, int x, int h, int w,
                                        float g0[3], float g1[3]) {
  #pragma unroll
  for (int c = 0; c < 3; ++c) {
    const float* p = base + (long)c * plane;
    float n[3][3];
    #pragma unroll
    for (int dy = 0; dy < 3; ++dy) {
      int yy = y + dy - 1;
      #pragma unroll
      for (int dx = 0; dx < 3; ++dx) {
        int xx = x + dx - 1;
        n[dy][dx] = (yy >= 0 && yy < h && xx >= 0 && xx < w) ? p[(long)yy * w + xx] : 0.0f;
      }
    }
    g0[c] = -3.0f*n[0][0] + 3.0f*n[0][2] + 10.0f*n[1][0] + 10.0f*n[1][2] - 3.0f*n[2][0] + 3.0f*n[2][2];
    g1[c] = -3.0f*n[0][0] + 10.0f*n[0][1] - 3.0f*n[0][2] + 3.0f*n[2][0] + 10.0f*n[2][1] + 3.0f*n[2][2];
  }
}

// g_rot at final output pixel (y,x): rotate-back (-45 deg) nearest sample into the
// 1449^2 rotated image, then 3x3 Scharr stencil there (zero if invalid).
__device__ __forceinline__ void grot3(const float* __restrict__ imgrot, int y, int x,
                                      float cb, float sb, float g0[3], float g1[3]) {
  float sx, sy;
  {
    #pragma clang fp contract(off)
    float dx = (float)(x + START) - 1024.5f;   // ncx of 2050-grid
    float dy = (float)(y + START) - 1024.5f;
    sx = cb*dx - sb*dy + 724.0f;               // cx of 1449-grid
    sy = sb*dx + cb*dy + 724.0f;
  }
  bool valid = (sx >= -0.5f) && (sx <= (float)RW - 0.5f) &&
               (sy >= -0.5f) && (sy <= (float)RH - 0.5f);
  if (!valid) {
    #pragma unroll
    for (int c = 0; c < 3; ++c) { g0[c] = 0.0f; g1[c] = 0.0f; }
    return;
  }
  int ix = min(max((int)rintf(sx), 0), RW - 1);
  int iy = min(max((int)rintf(sy), 0), RH - 1);
  scharr3(imgrot, (long)RA, iy, ix, RH, RW, g0, g1);
}

// ---------------- kernels ----------------

__global__ __launch_bounds__(256) void k_init(float* __restrict__ out, int* __restrict__ bbox) {
  int i = blockIdx.x * 256 + threadIdx.x;
  if (i < OUT_TOTAL) out[i] = 0.0f;
  if (i < 4 * NBSEG) bbox[i] = (i < 2 * NBSEG) ? INT_MAX : INT_MIN;
}

__global__ __launch_bounds__(256) void k_rot(const float* __restrict__ img,
                                             float* __restrict__ imgrot,
                                             float cf, float sf) {
  int p = blockIdx.x * 256 + threadIdx.x;
  if (p >= RA) return;
  int y = p / RW, x = p - y * RW;
  float sx, sy;
  {
    #pragma clang fp contract(off)
    float dx = (float)x - 724.0f;   // ncx of 1449-grid
    float dy = (float)y - 724.0f;
    sx = cf*dx - sf*dy + 511.5f;    // cx of 1024-grid
    sy = sf*dx + cf*dy + 511.5f;
  }
  bool valid = (sx >= -0.5f) && (sx <= 1023.5f) && (sy >= -0.5f) && (sy <= 1023.5f);
  int ix = min(max((int)rintf(sx), 0), WW - 1);
  int iy = min(max((int)rintf(sy), 0), HH - 1);
  int src = iy * WW + ix;
  imgrot[p]          = valid ? img[src] : 0.0f;
  imgrot[RA + p]     = valid ? img[NPIX + src] : 0.0f;
  imgrot[2*RA + p]   = valid ? img[2*NPIX + src] : 0.0f;
}

__global__ __launch_bounds__(256) void k_stats(const float* __restrict__ img,
                                               const int* __restrict__ reg,
                                               float* __restrict__ out,
                                               int* __restrict__ bbox) {
  int p = blockIdx.x * 256 + threadIdx.x;   // grid sized exactly NPIX
  int y = p >> 10, x = p & (WW - 1);
  int s = reg[p];
  if ((unsigned)s >= (unsigned)NBSEG) return;
  atomicMin(&bbox[s], x);
  atomicMin(&bbox[NBSEG + s], y);
  atomicMax(&bbox[2*NBSEG + s], x);
  atomicMax(&bbox[3*NBSEG + s], y);
  atomicAdd(&out[OUT_SIZE_OFF + s], 1.0f);
  float* ch = out + OUT_COLOR_OFF + s * 75;
  #pragma unroll
  for (int c = 0; c < 3; ++c) {
    int q = (int)(img[c * NPIX + p] * 24.0f);   // (img*(cb-1)).astype(int32)
    atomicAdd(&ch[c * 25 + q], 1.0f);
  }
}

__global__ __launch_bounds__(256) void k_minmax(const float* __restrict__ img,
                                                const float* __restrict__ imgrot,
                                                float* __restrict__ pmin,
                                                float* __restrict__ pmax,
                                                float cb, float sb) {
  int p = blockIdx.x * 256 + threadIdx.x;
  int y = p >> 10, x = p & (WW - 1);
  float a0[3], a1[3], b0[3], b1[3];
  scharr3(img, (long)NPIX, y, x, HH, WW, a0, a1);
  grot3(imgrot, y, x, cb, sb, b0, b1);
  float vmn[12], vmx[12];
  #pragma unroll
  for (int c = 0; c < 3; ++c) {
    vmn[2*c]     = vmx[2*c]     = a0[c];
    vmn[2*c + 1] = vmx[2*c + 1] = a1[c];
    vmn[6 + 2*c]     = vmx[6 + 2*c]     = b0[c];
    vmn[6 + 2*c + 1] = vmx[6 + 2*c + 1] = b1[c];
  }
  #pragma unroll
  for (int off = 32; off >= 1; off >>= 1) {
    #pragma unroll
    for (int m = 0; m < 12; ++m) {
      vmn[m] = fminf(vmn[m], __shfl_xor(vmn[m], off));
      vmx[m] = fmaxf(vmx[m], __shfl_xor(vmx[m], off));
    }
  }
  __shared__ float smn[12][4], smx[12][4];
  int wv = threadIdx.x >> 6;
  if ((threadIdx.x & 63) == 0) {
    #pragma unroll
    for (int m = 0; m < 12; ++m) { smn[m][wv] = vmn[m]; smx[m][wv] = vmx[m]; }
  }
  __syncthreads();
  if (threadIdx.x < 12) {
    int m = threadIdx.x;
    float mn = fminf(fminf(smn[m][0], smn[m][1]), fminf(smn[m][2], smn[m][3]));
    float mx = fmaxf(fmaxf(smx[m][0], smx[m][1]), fmaxf(smx[m][2], smx[m][3]));
    pmin[m * NBLK_PIX + blockIdx.x] = mn;
    pmax[m * NBLK_PIX + blockIdx.x] = mx;
  }
}

__global__ __launch_bounds__(256) void k_reduce(const float* __restrict__ pmin,
                                                const float* __restrict__ pmax,
                                                float* __restrict__ gmm) {
  int m = blockIdx.x;   // 0..11
  float mn = FLT_MAX, mx = -FLT_MAX;
  for (int i = threadIdx.x; i < NBLK_PIX; i += 256) {
    mn = fminf(mn, pmin[m * NBLK_PIX + i]);
    mx = fmaxf(mx, pmax[m * NBLK_PIX + i]);
  }
  #pragma unroll
  for (int off = 32; off >= 1; off >>= 1) {
    mn = fminf(mn, __shfl_xor(mn, off));
    mx = fmaxf(mx, __shfl_xor(mx, off));
  }
  __shared__ float smn[4], smx[4];
  int wv = threadIdx.x >> 6;
  if ((threadIdx.x & 63) == 0) { smn[wv] = mn; smx[wv] = mx; }
  __syncthreads();
  if (threadIdx.x == 0) {
    mn = fminf(fminf(smn[0], smn[1]), fminf(smn[2], smn[3]));
    mx = fmaxf(fmaxf(smx[0], smx[1]), fmaxf(smx[2], smx[3]));
    gmm[2*m] = mn; gmm[2*m + 1] = mx;
  }
}

// derive per-map (c,k) hmin & range from the 12 base-map min/max (relu is monotone)
__global__ void k_params(const float* __restrict__ gmm, float* __restrict__ params) {
  int t = threadIdx.x;
  if (t >= 24) return;
  int c = t / 8, k = t % 8;
  int base = (k < 4) ? (2*c + (k & 1)) : (6 + 2*c + (k & 1));
  bool pos = ((k >> 1) & 1) == 0;   // k in {0,1,4,5} -> max(.,0); {2,3,6,7} -> min(.,0)
  float mn = gmm[2*base], mx = gmm[2*base + 1];
  float hmin, hmax;
  if (pos) { hmin = fmaxf(mn, 0.0f); hmax = fmaxf(mx, 0.0f); }
  else     { hmin = fminf(mn, 0.0f); hmax = fminf(mx, 0.0f); }
  params[2*t]     = hmin;
  params[2*t + 1] = hmax - hmin;
}

__global__ __launch_bounds__(256) void k_tex(const float* __restrict__ img,
                                             const float* __restrict__ imgrot,
                                             const int* __restrict__ reg,
                                             const float* __restrict__ params,
                                             float* __restrict__ out,
                                             float cb, float sb) {
  int p = blockIdx.x * 256 + threadIdx.x;
  int y = p >> 10, x = p & (WW - 1);
  int s = reg[p];
  if ((unsigned)s >= (unsigned)NBSEG) return;
  float a0[3], a1[3], b0[3], b1[3];
  scharr3(img, (long)NPIX, y, x, HH, WW, a0, a1);
  grot3(imgrot, y, x, cb, sb, b0, b1);
  float* tex = out + OUT_TEX_OFF + s * 240;
  #pragma unroll
  for (int c = 0; c < 3; ++c) {
    float gv[2] = { a0[c], a1[c] };
    float rv[2] = { b0[c], b1[c] };
    #pragma unroll
    for (int d = 0; d < 2; ++d) {
      // k = d : max(g,0) ; k = 2+d : min(g,0) ; k = 4+d : max(grot,0) ; k = 6+d : min(grot,0)
      {
        int m = c*8 + d;
        float v = fmaxf(gv[d], 0.0f);
        int q = (int)(((v - params[2*m]) / params[2*m + 1]) * 9.0f);
        atomicAdd(&tex[c*80 + d*10 + q], 1.0f);
      }
      {
        int m = c*8 + 2 + d;
        float v = fminf(gv[d], 0.0f);
        int q = (int)(((v - params[2*m]) / params[2*m + 1]) * 9.0f);
        atomicAdd(&tex[c*80 + (2 + d)*10 + q], 1.0f);
      }
      {
        int m = c*8 + 4 + d;
        float v = fmaxf(rv[d], 0.0f);
        int q = (int)(((v - params[2*m]) / params[2*m + 1]) * 9.0f);
        atomicAdd(&tex[c*80 + (4 + d)*10 + q], 1.0f);
      }
      {
        int m = c*8 + 6 + d;
        float v = fminf(rv[d], 0.0f);
        int q = (int)(((v - params[2*m]) / params[2*m + 1]) * 9.0f);
        atomicAdd(&tex[c*80 + (6 + d)*10 + q], 1.0f);
      }
    }
  }
}

__global__ __launch_bounds__(64) void k_final(float* __restrict__ out,
                                              const int* __restrict__ bbox) {
  int s = blockIdx.x;
  float size = out[OUT_SIZE_OFF + s];
  if (threadIdx.x == 0) {
    int xmn = bbox[s], ymn = bbox[NBSEG + s];
    int xmx = bbox[2*NBSEG + s], ymx = bbox[3*NBSEG + s];
    out[4*s + 0] = (float)xmn;
    out[4*s + 1] = (float)ymn;
    out[4*s + 2] = (float)(xmx - xmn);
    out[4*s + 3] = (float)(ymx - ymn);
  }
  float cden = 3.0f * size, tden = 24.0f * size;
  bool ok = size > 0.0f;
  for (int i = threadIdx.x; i < 75; i += 64) {
    float v = out[OUT_COLOR_OFF + s*75 + i];
    out[OUT_COLOR_OFF + s*75 + i] = ok ? v / cden : 0.0f;
  }
  for (int i = threadIdx.x; i < 240; i += 64) {
    float v = out[OUT_TEX_OFF + s*240 + i];
    out[OUT_TEX_OFF + s*240 + i] = ok ? v / tden : 0.0f;
  }
}

// ---------------- launch ----------------

extern "C" void kernel_launch(void* const* d_in, const int* in_sizes, int n_in,
                              void* d_out, int out_size, void* d_ws, size_t ws_size,
                              hipStream_t stream) {
  const float* img = (const float*)d_in[0];
  const int*   reg = (const int*)d_in[1];   // reg_lab (int32 after JAX canonicalization)
  float* out = (float*)d_out;

  char* ws = (char*)d_ws;
  size_t off = 0;
  float* imgrot = (float*)(ws + off); off += (size_t)3 * RA * 4;  off = (off + 255) & ~(size_t)255;
  int*   bbox   = (int*)(ws + off);   off += (size_t)4 * NBSEG * 4; off = (off + 255) & ~(size_t)255;
  float* pmin   = (float*)(ws + off); off += (size_t)12 * NBLK_PIX * 4;
  float* pmax   = (float*)(ws + off); off += (size_t)12 * NBLK_PIX * 4;
  float* gmm    = (float*)(ws + off); off += 24 * 4;
  float* params = (float*)(ws + off); off += 48 * 4;
  (void)ws_size; (void)in_sizes; (void)n_in; (void)out_size;

  // rotation constants, replicating math.radians + cos/sin in double then f32 cast
  double th  = 45.0 * (M_PI / 180.0);
  float cf = (float)cos(th),  sf = (float)sin(th);    // forward +45
  double thb = -45.0 * (M_PI / 180.0);
  float cbk = (float)cos(thb), sbk = (float)sin(thb); // backward -45

  k_init  <<<(OUT_TOTAL + 255) / 256, 256, 0, stream>>>(out, bbox);
  k_rot   <<<(RA + 255) / 256,       256, 0, stream>>>(img, imgrot, cf, sf);
  k_stats <<<NBLK_PIX,               256, 0, stream>>>(img, reg, out, bbox);
  k_minmax<<<NBLK_PIX,               256, 0, stream>>>(img, imgrot, pmin, pmax, cbk, sbk);
  k_reduce<<<12,                     256, 0, stream>>>(pmin, pmax, gmm);
  k_params<<<1,                      32,  0, stream>>>(gmm, params);
  k_tex   <<<NBLK_PIX,               256, 0, stream>>>(img, imgrot, reg, params, out, cbk, sbk);
  k_final <<<NBSEG,                  64,  0, stream>>>(out, bbox);
}

// Round 2
// 410.677 us; speedup vs baseline: 4.4692x; 4.4692x over previous
//
#include <hip/hip_runtime.h>
#include <math.h>
#include <float.h>
#include <limits.h>

// ---------------- problem constants (fixed by setup_inputs) ----------------
#define HH 1024
#define WW 1024
#define NPIX (HH*WW)          // 1048576
#define RH 1449               // ceil(1024*sqrt(2))
#define RW 1449
#define RA (RH*RW)            // 2099601
#define NBSEG 5000
#define START 211             // int((rot_bbox_w - 1024)/2) for 45 deg
#define NBLK_PIX (NPIX/256)   // 4096

// output layout (floats, concatenated in return order)
#define OUT_XYWH_OFF  0          // 5000*4
#define OUT_SIZE_OFF  20000      // 5000
#define OUT_COLOR_OFF 25000      // 5000*3*25
#define OUT_TEX_OFF   400000     // 5000*3*8*10
#define OUT_TOTAL     1600000

// ---------------- device helpers ----------------

// 3x3 zero-padded cross-correlation with kx=[[-3,0,3],[10,0,10],[-3,0,3]] and kx^T,
// for all 3 channels of a planar image. (XLA conv_general_dilated = cross-correlation.)
__device__ __forceinline__ void scharr3(const float* __restrict__ base, long plane,
                                        int y, int x, int h, int w,
                                        float g0[3], float g1[3]) {
  #pragma unroll
  for (int c = 0; c < 3; ++c) {
    const float* p = base + (long)c * plane;
    float n[3][3];
    #pragma unroll
    for (int dy = 0; dy < 3; ++dy) {
      int yy = y + dy - 1;
      #pragma unroll
      for (int dx = 0; dx < 3; ++dx) {
        int xx = x + dx - 1;
        n[dy][dx] = (yy >= 0 && yy < h && xx >= 0 && xx < w) ? p[(long)yy * w + xx] : 0.0f;
      }
    }
    g0[c] = -3.0f*n[0][0] + 3.0f*n[0][2] + 10.0f*n[1][0] + 10.0f*n[1][2] - 3.0f*n[2][0] + 3.0f*n[2][2];
    g1[c] = -3.0f*n[0][0] + 10.0f*n[0][1] - 3.0f*n[0][2] + 3.0f*n[2][0] + 10.0f*n[2][1] + 3.0f*n[2][2];
  }
}

// g_rot at final output pixel (y,x): rotate-back (-45 deg) nearest sample into the
// 1449^2 rotated image, then 3x3 Scharr stencil there (zero if invalid).
__device__ __forceinline__ void grot3(const float* __restrict__ imgrot, int y, int x,
                                      float cb, float sb, float g0[3], float g1[3]) {
  float sx, sy;
  {
    #pragma clang fp contract(off)
    float dx = (float)(x + START) - 1024.5f;   // ncx of 2050-grid
    float dy = (float)(y + START) - 1024.5f;
    sx = cb*dx - sb*dy + 724.0f;               // cx of 1449-grid
    sy = sb*dx + cb*dy + 724.0f;
  }
  bool valid = (sx >= -0.5f) && (sx <= (float)RW - 0.5f) &&
               (sy >= -0.5f) && (sy <= (float)RH - 0.5f);
  if (!valid) {
    #pragma unroll
    for (int c = 0; c < 3; ++c) { g0[c] = 0.0f; g1[c] = 0.0f; }
    return;
  }
  int ix = min(max((int)rintf(sx), 0), RW - 1);
  int iy = min(max((int)rintf(sy), 0), RH - 1);
  scharr3(imgrot, (long)RA, iy, ix, RH, RW, g0, g1);
}

// ---------------- kernels ----------------

__global__ __launch_bounds__(256) void k_zero(int* __restrict__ cnt) {
  int i = blockIdx.x * 256 + threadIdx.x;
  if (i < 5120) cnt[i] = 0;
}

__global__ __launch_bounds__(256) void k_rot(const float* __restrict__ img,
                                             float* __restrict__ imgrot,
                                             float cf, float sf) {
  int p = blockIdx.x * 256 + threadIdx.x;
  if (p >= RA) return;
  int y = p / RW, x = p - y * RW;
  float sx, sy;
  {
    #pragma clang fp contract(off)
    float dx = (float)x - 724.0f;   // ncx of 1449-grid
    float dy = (float)y - 724.0f;
    sx = cf*dx - sf*dy + 511.5f;    // cx of 1024-grid
    sy = sf*dx + cf*dy + 511.5f;
  }
  bool valid = (sx >= -0.5f) && (sx <= 1023.5f) && (sy >= -0.5f) && (sy <= 1023.5f);
  int ix = min(max((int)rintf(sx), 0), WW - 1);
  int iy = min(max((int)rintf(sy), 0), HH - 1);
  int src = iy * WW + ix;
  imgrot[p]          = valid ? img[src] : 0.0f;
  imgrot[RA + p]     = valid ? img[NPIX + src] : 0.0f;
  imgrot[2*RA + p]   = valid ? img[2*NPIX + src] : 0.0f;
}

// gradient min/max partials + segment counting (fused)
__global__ __launch_bounds__(256) void k_minmax(const float* __restrict__ img,
                                                const float* __restrict__ imgrot,
                                                const int* __restrict__ reg,
                                                int* __restrict__ cnt,
                                                float* __restrict__ pmin,
                                                float* __restrict__ pmax,
                                                float cb, float sb) {
  int p = blockIdx.x * 256 + threadIdx.x;
  int y = p >> 10, x = p & (WW - 1);
  int s = reg[p];
  if ((unsigned)s < (unsigned)NBSEG) atomicAdd(&cnt[s], 1);
  float a0[3], a1[3], b0[3], b1[3];
  scharr3(img, (long)NPIX, y, x, HH, WW, a0, a1);
  grot3(imgrot, y, x, cb, sb, b0, b1);
  float vmn[12], vmx[12];
  #pragma unroll
  for (int c = 0; c < 3; ++c) {
    vmn[2*c]     = vmx[2*c]     = a0[c];
    vmn[2*c + 1] = vmx[2*c + 1] = a1[c];
    vmn[6 + 2*c]     = vmx[6 + 2*c]     = b0[c];
    vmn[6 + 2*c + 1] = vmx[6 + 2*c + 1] = b1[c];
  }
  #pragma unroll
  for (int off = 32; off >= 1; off >>= 1) {
    #pragma unroll
    for (int m = 0; m < 12; ++m) {
      vmn[m] = fminf(vmn[m], __shfl_xor(vmn[m], off));
      vmx[m] = fmaxf(vmx[m], __shfl_xor(vmx[m], off));
    }
  }
  __shared__ float smn[12][4], smx[12][4];
  int wv = threadIdx.x >> 6;
  if ((threadIdx.x & 63) == 0) {
    #pragma unroll
    for (int m = 0; m < 12; ++m) { smn[m][wv] = vmn[m]; smx[m][wv] = vmx[m]; }
  }
  __syncthreads();
  if (threadIdx.x < 12) {
    int m = threadIdx.x;
    float mn = fminf(fminf(smn[m][0], smn[m][1]), fminf(smn[m][2], smn[m][3]));
    float mx = fmaxf(fmaxf(smx[m][0], smx[m][1]), fmaxf(smx[m][2], smx[m][3]));
    pmin[m * NBLK_PIX + blockIdx.x] = mn;
    pmax[m * NBLK_PIX + blockIdx.x] = mx;
  }
}

__global__ __launch_bounds__(256) void k_reduce(const float* __restrict__ pmin,
                                                const float* __restrict__ pmax,
                                                float* __restrict__ gmm) {
  int m = blockIdx.x;   // 0..11
  float mn = FLT_MAX, mx = -FLT_MAX;
  for (int i = threadIdx.x; i < NBLK_PIX; i += 256) {
    mn = fminf(mn, pmin[m * NBLK_PIX + i]);
    mx = fmaxf(mx, pmax[m * NBLK_PIX + i]);
  }
  #pragma unroll
  for (int off = 32; off >= 1; off >>= 1) {
    mn = fminf(mn, __shfl_xor(mn, off));
    mx = fmaxf(mx, __shfl_xor(mx, off));
  }
  __shared__ float smn[4], smx[4];
  int wv = threadIdx.x >> 6;
  if ((threadIdx.x & 63) == 0) { smn[wv] = mn; smx[wv] = mx; }
  __syncthreads();
  if (threadIdx.x == 0) {
    mn = fminf(fminf(smn[0], smn[1]), fminf(smn[2], smn[3]));
    mx = fmaxf(fmaxf(smx[0], smx[1]), fmaxf(smx[2], smx[3]));
    gmm[2*m] = mn; gmm[2*m + 1] = mx;
  }
}

// derive per-map (c,k) hmin & range from the 12 base-map min/max (relu is monotone)
__global__ void k_params(const float* __restrict__ gmm, float* __restrict__ params) {
  int t = threadIdx.x;
  if (t >= 24) return;
  int c = t / 8, k = t % 8;
  int base = (k < 4) ? (2*c + (k & 1)) : (6 + 2*c + (k & 1));
  bool pos = ((k >> 1) & 1) == 0;   // k in {0,1,4,5} -> max(.,0); {2,3,6,7} -> min(.,0)
  float mn = gmm[2*base], mx = gmm[2*base + 1];
  float hmin, hmax;
  if (pos) { hmin = fmaxf(mn, 0.0f); hmax = fmaxf(mx, 0.0f); }
  else     { hmin = fminf(mn, 0.0f); hmax = fminf(mx, 0.0f); }
  params[2*t]     = hmin;
  params[2*t + 1] = hmax - hmin;
}

// exclusive prefix scan of 5000 segment counts -> start[5001], offs (cursors)
__global__ __launch_bounds__(1024) void k_scan(const int* __restrict__ cnt,
                                               int* __restrict__ start,
                                               int* __restrict__ offs) {
  __shared__ int part[1024];
  int t = threadIdx.x;
  int base = t * 5;
  int v[5]; int sum = 0;
  #pragma unroll
  for (int j = 0; j < 5; ++j) {
    v[j] = (base + j < NBSEG) ? cnt[base + j] : 0;
    sum += v[j];
  }
  part[t] = sum;
  __syncthreads();
  #pragma unroll
  for (int d = 1; d < 1024; d <<= 1) {
    int xv = (t >= d) ? part[t - d] : 0;
    __syncthreads();
    part[t] += xv;
    __syncthreads();
  }
  int run = (t > 0) ? part[t - 1] : 0;   // exclusive
  #pragma unroll
  for (int j = 0; j < 5; ++j) {
    int i = base + j;
    if (i <= NBSEG) start[i] = run;
    if (i < NBSEG)  offs[i] = run;
    run += v[j];
  }
}

// per-pixel: compute all bins exactly as reference, pack into uint4, scatter by segment
__global__ __launch_bounds__(256) void k_binrec(const float* __restrict__ img,
                                                const float* __restrict__ imgrot,
                                                const int* __restrict__ reg,
                                                const float* __restrict__ params,
                                                int* __restrict__ offs,
                                                uint4* __restrict__ rec,
                                                float cb, float sb) {
  int p = blockIdx.x * 256 + threadIdx.x;
  int y = p >> 10, x = p & (WW - 1);
  int s = reg[p];
  if ((unsigned)s >= (unsigned)NBSEG) return;
  float a0[3], a1[3], b0[3], b1[3];
  scharr3(img, (long)NPIX, y, x, HH, WW, a0, a1);
  grot3(imgrot, y, x, cb, sb, b0, b1);

  unsigned q[24];
  #pragma unroll
  for (int c = 0; c < 3; ++c) {
    float gv[2] = { a0[c], a1[c] };
    float rv[2] = { b0[c], b1[c] };
    #pragma unroll
    for (int d = 0; d < 2; ++d) {
      {
        int m = c*8 + d;
        float v = fmaxf(gv[d], 0.0f);
        int qq = (int)(((v - params[2*m]) / params[2*m + 1]) * 9.0f);
        q[m] = (unsigned)min(max(qq, 0), 9);
      }
      {
        int m = c*8 + 2 + d;
        float v = fminf(gv[d], 0.0f);
        int qq = (int)(((v - params[2*m]) / params[2*m + 1]) * 9.0f);
        q[m] = (unsigned)min(max(qq, 0), 9);
      }
      {
        int m = c*8 + 4 + d;
        float v = fmaxf(rv[d], 0.0f);
        int qq = (int)(((v - params[2*m]) / params[2*m + 1]) * 9.0f);
        q[m] = (unsigned)min(max(qq, 0), 9);
      }
      {
        int m = c*8 + 6 + d;
        float v = fminf(rv[d], 0.0f);
        int qq = (int)(((v - params[2*m]) / params[2*m + 1]) * 9.0f);
        q[m] = (unsigned)min(max(qq, 0), 9);
      }
    }
  }
  unsigned qc[3];
  #pragma unroll
  for (int c = 0; c < 3; ++c) {
    int cc = (int)(img[c * NPIX + p] * 24.0f);   // (img*(cb-1)).astype(int32)
    qc[c] = (unsigned)min(max(cc, 0), 24);
  }

  unsigned trip[8];
  #pragma unroll
  for (int j = 0; j < 8; ++j)
    trip[j] = q[3*j] + 10u*q[3*j + 1] + 100u*q[3*j + 2];
  unsigned cp = qc[0] + 25u*qc[1] + 625u*qc[2];

  uint4 r;
  r.x = (unsigned)p | (trip[0] << 20);
  r.y = trip[1] | (trip[2] << 10) | (trip[3] << 20);
  r.z = trip[4] | (trip[5] << 10) | (trip[6] << 20);
  r.w = trip[7] | (cp << 10);

  int pos = atomicAdd(&offs[s], 1);
  rec[pos] = r;
}

// one block per segment: LDS integer histograms + bbox, fused normalization, single write
__global__ __launch_bounds__(256) void k_accum(const uint4* __restrict__ rec,
                                               const int* __restrict__ start,
                                               float* __restrict__ out) {
  int s = blockIdx.x;
  int beg = start[s], end = start[s + 1];
  int n = end - beg;
  __shared__ unsigned hist[240 + 75];
  __shared__ int bb[4];
  for (int i = threadIdx.x; i < 240 + 75; i += 256) hist[i] = 0;
  if (threadIdx.x == 0) { bb[0] = INT_MAX; bb[1] = INT_MAX; bb[2] = INT_MIN; bb[3] = INT_MIN; }
  __syncthreads();

  for (int i = beg + threadIdx.x; i < end; i += 256) {
    uint4 r = rec[i];
    unsigned p = r.x & 0xFFFFFu;
    int x = (int)(p & 1023u), y = (int)(p >> 10);
    atomicMin(&bb[0], x); atomicMin(&bb[1], y);
    atomicMax(&bb[2], x); atomicMax(&bb[3], y);
    unsigned trip[8];
    trip[0] = (r.x >> 20) & 0x3FFu;
    trip[1] = r.y & 0x3FFu; trip[2] = (r.y >> 10) & 0x3FFu; trip[3] = (r.y >> 20) & 0x3FFu;
    trip[4] = r.z & 0x3FFu; trip[5] = (r.z >> 10) & 0x3FFu; trip[6] = (r.z >> 20) & 0x3FFu;
    trip[7] = r.w & 0x3FFu;
    unsigned cp = r.w >> 10;
    #pragma unroll
    for (int j = 0; j < 8; ++j) {
      unsigned t = trip[j];
      unsigned q2 = t / 100u; unsigned rr = t - 100u*q2;
      unsigned q1 = rr / 10u; unsigned q0 = rr - 10u*q1;
      atomicAdd(&hist[(3*j + 0)*10 + q0], 1u);
      atomicAdd(&hist[(3*j + 1)*10 + q1], 1u);
      atomicAdd(&hist[(3*j + 2)*10 + q2], 1u);
    }
    unsigned c0 = cp % 25u; unsigned rem = cp / 25u;
    unsigned c1 = rem % 25u; unsigned c2 = rem / 25u;
    atomicAdd(&hist[240 + 0*25 + c0], 1u);
    atomicAdd(&hist[240 + 1*25 + c1], 1u);
    atomicAdd(&hist[240 + 2*25 + c2], 1u);
  }
  __syncthreads();

  if (threadIdx.x == 0) {
    out[4*s + 0] = (float)bb[0];
    out[4*s + 1] = (float)bb[1];
    out[4*s + 2] = (float)(bb[2] - bb[0]);
    out[4*s + 3] = (float)(bb[3] - bb[1]);
    out[OUT_SIZE_OFF + s] = (float)n;
  }
  bool ok = n > 0;
  float cden = 3.0f * (float)n, tden = 24.0f * (float)n;
  for (int i = threadIdx.x; i < 240; i += 256)
    out[OUT_TEX_OFF + s*240 + i] = ok ? (float)hist[i] / tden : 0.0f;
  for (int i = threadIdx.x; i < 75; i += 256)
    out[OUT_COLOR_OFF + s*75 + i] = ok ? (float)hist[240 + i] / cden : 0.0f;
}

// ---------------- launch ----------------

extern "C" void kernel_launch(void* const* d_in, const int* in_sizes, int n_in,
                              void* d_out, int out_size, void* d_ws, size_t ws_size,
                              hipStream_t stream) {
  const float* img = (const float*)d_in[0];
  const int*   reg = (const int*)d_in[1];
  float* out = (float*)d_out;

  char* ws = (char*)d_ws;
  size_t off = 0;
  float* imgrot = (float*)(ws + off); off += (size_t)3 * RA * 4;   off = (off + 255) & ~(size_t)255;
  int*   cnt    = (int*)(ws + off);   off += 5120 * 4;
  int*   start  = (int*)(ws + off);   off += 5008 * 4;
  int*   offs   = (int*)(ws + off);   off += 5008 * 4;
  float* gmm    = (float*)(ws + off); off += 32 * 4;
  float* params = (float*)(ws + off); off += 64 * 4;               off = (off + 255) & ~(size_t)255;
  // pmin/pmax (dead after k_reduce) overlap with rec (written in k_binrec)
  float* pmin   = (float*)(ws + off);
  float* pmax   = pmin + 12 * NBLK_PIX;
  uint4* rec    = (uint4*)(ws + off);
  (void)ws_size; (void)in_sizes; (void)n_in; (void)out_size;

  double th  = 45.0 * (M_PI / 180.0);
  float cf = (float)cos(th),  sf = (float)sin(th);    // forward +45
  double thb = -45.0 * (M_PI / 180.0);
  float cbk = (float)cos(thb), sbk = (float)sin(thb); // backward -45

  k_zero  <<<20,                 256,  0, stream>>>(cnt);
  k_rot   <<<(RA + 255) / 256,   256,  0, stream>>>(img, imgrot, cf, sf);
  k_minmax<<<NBLK_PIX,           256,  0, stream>>>(img, imgrot, reg, cnt, pmin, pmax, cbk, sbk);
  k_reduce<<<12,                 256,  0, stream>>>(pmin, pmax, gmm);
  k_params<<<1,                  32,   0, stream>>>(gmm, params);
  k_scan  <<<1,                  1024, 0, stream>>>(cnt, start, offs);
  k_binrec<<<NBLK_PIX,           256,  0, stream>>>(img, imgrot, reg, params, offs, rec, cbk, sbk);
  k_accum <<<NBSEG,              256,  0, stream>>>(rec, start, out);
}

// Round 3
// 370.006 us; speedup vs baseline: 4.9605x; 1.1099x over previous
//
#include <hip/hip_runtime.h>
#include <math.h>
#include <float.h>
#include <limits.h>

// ---------------- problem constants (fixed by setup_inputs) ----------------
#define HH 1024
#define WW 1024
#define NPIX (HH*WW)          // 1048576
#define RH 1449               // ceil(1024*sqrt(2))
#define RW 1449
#define RA (RH*RW)            // 2099601
#define NBSEG 5000
#define START 211             // int((rot_bbox_w - 1024)/2) for 45 deg
#define NBLK_PIX (NPIX/256)   // 4096

// output layout (floats, concatenated in return order)
#define OUT_XYWH_OFF  0          // 5000*4
#define OUT_SIZE_OFF  20000      // 5000
#define OUT_COLOR_OFF 25000      // 5000*3*25
#define OUT_TEX_OFF   400000     // 5000*3*8*10
#define OUT_TOTAL     1600000

// ---------------- device helpers ----------------

// 3x3 zero-padded cross-correlation with kx=[[-3,0,3],[10,0,10],[-3,0,3]] and kx^T,
// for all 3 channels of a planar image. (XLA conv_general_dilated = cross-correlation.)
__device__ __forceinline__ void scharr3(const float* __restrict__ base, long plane,
                                        int y, int x, int h, int w,
                                        float g0[3], float g1[3]) {
  #pragma unroll
  for (int c = 0; c < 3; ++c) {
    const float* p = base + (long)c * plane;
    float n[3][3];
    #pragma unroll
    for (int dy = 0; dy < 3; ++dy) {
      int yy = y + dy - 1;
      #pragma unroll
      for (int dx = 0; dx < 3; ++dx) {
        int xx = x + dx - 1;
        n[dy][dx] = (yy >= 0 && yy < h && xx >= 0 && xx < w) ? p[(long)yy * w + xx] : 0.0f;
      }
    }
    g0[c] = -3.0f*n[0][0] + 3.0f*n[0][2] + 10.0f*n[1][0] + 10.0f*n[1][2] - 3.0f*n[2][0] + 3.0f*n[2][2];
    g1[c] = -3.0f*n[0][0] + 10.0f*n[0][1] - 3.0f*n[0][2] + 3.0f*n[2][0] + 10.0f*n[2][1] + 3.0f*n[2][2];
  }
}

// back-rotation sample coords for final pixel (y,x) into the 1449^2 rotated grid
__device__ __forceinline__ void backmap(int y, int x, float cb, float sb,
                                        bool& valid, int& iy, int& ix) {
  float sx, sy;
  {
    #pragma clang fp contract(off)
    float dx = (float)(x + START) - 1024.5f;   // ncx of 2050-grid
    float dy = (float)(y + START) - 1024.5f;
    sx = cb*dx - sb*dy + 724.0f;               // cx of 1449-grid
    sy = sb*dx + cb*dy + 724.0f;
  }
  valid = (sx >= -0.5f) && (sx <= (float)RW - 0.5f) &&
          (sy >= -0.5f) && (sy <= (float)RH - 0.5f);
  ix = min(max((int)rintf(sx), 0), RW - 1);
  iy = min(max((int)rintf(sy), 0), RH - 1);
}

// ---------------- kernels ----------------

__global__ __launch_bounds__(256) void k_zero(int* __restrict__ cnt) {
  int i = blockIdx.x * 256 + threadIdx.x;
  if (i < 5120) cnt[i] = 0;
}

__global__ __launch_bounds__(256) void k_rot(const float* __restrict__ img,
                                             float* __restrict__ imgrot,
                                             float cf, float sf) {
  int p = blockIdx.x * 256 + threadIdx.x;
  if (p >= RA) return;
  int y = p / RW, x = p - y * RW;
  float sx, sy;
  {
    #pragma clang fp contract(off)
    float dx = (float)x - 724.0f;   // ncx of 1449-grid
    float dy = (float)y - 724.0f;
    sx = cf*dx - sf*dy + 511.5f;    // cx of 1024-grid
    sy = sf*dx + cf*dy + 511.5f;
  }
  bool valid = (sx >= -0.5f) && (sx <= 1023.5f) && (sy >= -0.5f) && (sy <= 1023.5f);
  int ix = min(max((int)rintf(sx), 0), WW - 1);
  int iy = min(max((int)rintf(sy), 0), HH - 1);
  int src = iy * WW + ix;
  imgrot[p]          = valid ? img[src] : 0.0f;
  imgrot[RA + p]     = valid ? img[NPIX + src] : 0.0f;
  imgrot[2*RA + p]   = valid ? img[2*NPIX + src] : 0.0f;
}

// Scharr over the rotated image in natural (coalesced) layout.
// grot[p*6 + 2c + d] = dir-d gradient of channel c at rotated-grid point p.
__global__ __launch_bounds__(256) void k_gradrot(const float* __restrict__ imgrot,
                                                 float* __restrict__ grot) {
  int p = blockIdx.x * 256 + threadIdx.x;
  if (p >= RA) return;
  int y = p / RW, x = p - y * RW;
  float g0[3], g1[3];
  scharr3(imgrot, (long)RA, y, x, RH, RW, g0, g1);
  float2* g2 = (float2*)(grot + (long)p * 6);
  g2[0] = make_float2(g0[0], g1[0]);
  g2[1] = make_float2(g0[1], g1[1]);
  g2[2] = make_float2(g0[2], g1[2]);
}

// Per final pixel: img-Scharr (coalesced) + point-sample of rotated gradients
// (3 scattered float2 loads). Emits 12-map min/max partials, segment counts,
// and the 6 sampled rot-gradients to SoA planes srot for k_binrec.
__global__ __launch_bounds__(256) void k_sample(const float* __restrict__ img,
                                                const float* __restrict__ grot,
                                                const int* __restrict__ reg,
                                                int* __restrict__ cnt,
                                                float* __restrict__ srot,
                                                float* __restrict__ pmin,
                                                float* __restrict__ pmax,
                                                float cb, float sb) {
  int p = blockIdx.x * 256 + threadIdx.x;
  int y = p >> 10, x = p & (WW - 1);
  int s = reg[p];
  if ((unsigned)s < (unsigned)NBSEG) atomicAdd(&cnt[s], 1);

  float a0[3], a1[3], b0[3], b1[3];
  scharr3(img, (long)NPIX, y, x, HH, WW, a0, a1);

  bool valid; int iy, ix;
  backmap(y, x, cb, sb, valid, iy, ix);
  if (valid) {
    const float2* g2 = (const float2*)(grot + (long)(iy * RW + ix) * 6);
    float2 v0 = g2[0], v1 = g2[1], v2 = g2[2];
    b0[0] = v0.x; b1[0] = v0.y;
    b0[1] = v1.x; b1[1] = v1.y;
    b0[2] = v2.x; b1[2] = v2.y;
  } else {
    #pragma unroll
    for (int c = 0; c < 3; ++c) { b0[c] = 0.0f; b1[c] = 0.0f; }
  }
  #pragma unroll
  for (int c = 0; c < 3; ++c) {
    srot[(2*c)     * NPIX + p] = b0[c];
    srot[(2*c + 1) * NPIX + p] = b1[c];
  }

  float vmn[12], vmx[12];
  #pragma unroll
  for (int c = 0; c < 3; ++c) {
    vmn[2*c]     = vmx[2*c]     = a0[c];
    vmn[2*c + 1] = vmx[2*c + 1] = a1[c];
    vmn[6 + 2*c]     = vmx[6 + 2*c]     = b0[c];
    vmn[6 + 2*c + 1] = vmx[6 + 2*c + 1] = b1[c];
  }
  #pragma unroll
  for (int off = 32; off >= 1; off >>= 1) {
    #pragma unroll
    for (int m = 0; m < 12; ++m) {
      vmn[m] = fminf(vmn[m], __shfl_xor(vmn[m], off));
      vmx[m] = fmaxf(vmx[m], __shfl_xor(vmx[m], off));
    }
  }
  __shared__ float smn[12][4], smx[12][4];
  int wv = threadIdx.x >> 6;
  if ((threadIdx.x & 63) == 0) {
    #pragma unroll
    for (int m = 0; m < 12; ++m) { smn[m][wv] = vmn[m]; smx[m][wv] = vmx[m]; }
  }
  __syncthreads();
  if (threadIdx.x < 12) {
    int m = threadIdx.x;
    float mn = fminf(fminf(smn[m][0], smn[m][1]), fminf(smn[m][2], smn[m][3]));
    float mx = fmaxf(fmaxf(smx[m][0], smx[m][1]), fmaxf(smx[m][2], smx[m][3]));
    pmin[m * NBLK_PIX + blockIdx.x] = mn;
    pmax[m * NBLK_PIX + blockIdx.x] = mx;
  }
}

__global__ __launch_bounds__(256) void k_reduce(const float* __restrict__ pmin,
                                                const float* __restrict__ pmax,
                                                float* __restrict__ gmm) {
  int m = blockIdx.x;   // 0..11
  float mn = FLT_MAX, mx = -FLT_MAX;
  for (int i = threadIdx.x; i < NBLK_PIX; i += 256) {
    mn = fminf(mn, pmin[m * NBLK_PIX + i]);
    mx = fmaxf(mx, pmax[m * NBLK_PIX + i]);
  }
  #pragma unroll
  for (int off = 32; off >= 1; off >>= 1) {
    mn = fminf(mn, __shfl_xor(mn, off));
    mx = fmaxf(mx, __shfl_xor(mx, off));
  }
  __shared__ float smn[4], smx[4];
  int wv = threadIdx.x >> 6;
  if ((threadIdx.x & 63) == 0) { smn[wv] = mn; smx[wv] = mx; }
  __syncthreads();
  if (threadIdx.x == 0) {
    mn = fminf(fminf(smn[0], smn[1]), fminf(smn[2], smn[3]));
    mx = fmaxf(fmaxf(smx[0], smx[1]), fmaxf(smx[2], smx[3]));
    gmm[2*m] = mn; gmm[2*m + 1] = mx;
  }
}

// derive per-map (c,k) hmin & range from the 12 base-map min/max (relu is monotone)
__global__ void k_params(const float* __restrict__ gmm, float* __restrict__ params) {
  int t = threadIdx.x;
  if (t >= 24) return;
  int c = t / 8, k = t % 8;
  int base = (k < 4) ? (2*c + (k & 1)) : (6 + 2*c + (k & 1));
  bool pos = ((k >> 1) & 1) == 0;   // k in {0,1,4,5} -> max(.,0); {2,3,6,7} -> min(.,0)
  float mn = gmm[2*base], mx = gmm[2*base + 1];
  float hmin, hmax;
  if (pos) { hmin = fmaxf(mn, 0.0f); hmax = fmaxf(mx, 0.0f); }
  else     { hmin = fminf(mn, 0.0f); hmax = fminf(mx, 0.0f); }
  params[2*t]     = hmin;
  params[2*t + 1] = hmax - hmin;
}

// exclusive prefix scan of 5000 segment counts -> start[5001], offs (cursors)
__global__ __launch_bounds__(1024) void k_scan(const int* __restrict__ cnt,
                                               int* __restrict__ start,
                                               int* __restrict__ offs) {
  __shared__ int part[1024];
  int t = threadIdx.x;
  int base = t * 5;
  int v[5]; int sum = 0;
  #pragma unroll
  for (int j = 0; j < 5; ++j) {
    v[j] = (base + j < NBSEG) ? cnt[base + j] : 0;
    sum += v[j];
  }
  part[t] = sum;
  __syncthreads();
  #pragma unroll
  for (int d = 1; d < 1024; d <<= 1) {
    int xv = (t >= d) ? part[t - d] : 0;
    __syncthreads();
    part[t] += xv;
    __syncthreads();
  }
  int run = (t > 0) ? part[t - 1] : 0;   // exclusive
  #pragma unroll
  for (int j = 0; j < 5; ++j) {
    int i = base + j;
    if (i <= NBSEG) start[i] = run;
    if (i < NBSEG)  offs[i] = run;
    run += v[j];
  }
}

// per-pixel: compute all bins exactly as reference, pack into uint4, scatter by segment
__global__ __launch_bounds__(256) void k_binrec(const float* __restrict__ img,
                                                const float* __restrict__ srot,
                                                const int* __restrict__ reg,
                                                const float* __restrict__ params,
                                                int* __restrict__ offs,
                                                uint4* __restrict__ rec) {
  int p = blockIdx.x * 256 + threadIdx.x;
  int y = p >> 10, x = p & (WW - 1);
  int s = reg[p];
  if ((unsigned)s >= (unsigned)NBSEG) return;
  float a0[3], a1[3], b0[3], b1[3];
  scharr3(img, (long)NPIX, y, x, HH, WW, a0, a1);
  #pragma unroll
  for (int c = 0; c < 3; ++c) {
    b0[c] = srot[(2*c)     * NPIX + p];
    b1[c] = srot[(2*c + 1) * NPIX + p];
  }

  unsigned q[24];
  #pragma unroll
  for (int c = 0; c < 3; ++c) {
    float gv[2] = { a0[c], a1[c] };
    float rv[2] = { b0[c], b1[c] };
    #pragma unroll
    for (int d = 0; d < 2; ++d) {
      {
        int m = c*8 + d;
        float v = fmaxf(gv[d], 0.0f);
        int qq = (int)(((v - params[2*m]) / params[2*m + 1]) * 9.0f);
        q[m] = (unsigned)min(max(qq, 0), 9);
      }
      {
        int m = c*8 + 2 + d;
        float v = fminf(gv[d], 0.0f);
        int qq = (int)(((v - params[2*m]) / params[2*m + 1]) * 9.0f);
        q[m] = (unsigned)min(max(qq, 0), 9);
      }
      {
        int m = c*8 + 4 + d;
        float v = fmaxf(rv[d], 0.0f);
        int qq = (int)(((v - params[2*m]) / params[2*m + 1]) * 9.0f);
        q[m] = (unsigned)min(max(qq, 0), 9);
      }
      {
        int m = c*8 + 6 + d;
        float v = fminf(rv[d], 0.0f);
        int qq = (int)(((v - params[2*m]) / params[2*m + 1]) * 9.0f);
        q[m] = (unsigned)min(max(qq, 0), 9);
      }
    }
  }
  unsigned qc[3];
  #pragma unroll
  for (int c = 0; c < 3; ++c) {
    int cc = (int)(img[c * NPIX + p] * 24.0f);   // (img*(cb-1)).astype(int32)
    qc[c] = (unsigned)min(max(cc, 0), 24);
  }

  unsigned trip[8];
  #pragma unroll
  for (int j = 0; j < 8; ++j)
    trip[j] = q[3*j] + 10u*q[3*j + 1] + 100u*q[3*j + 2];
  unsigned cp = qc[0] + 25u*qc[1] + 625u*qc[2];

  uint4 r;
  r.x = (unsigned)p | (trip[0] << 20);
  r.y = trip[1] | (trip[2] << 10) | (trip[3] << 20);
  r.z = trip[4] | (trip[5] << 10) | (trip[6] << 20);
  r.w = trip[7] | (cp << 10);

  int pos = atomicAdd(&offs[s], 1);
  rec[pos] = r;
}

// one block per segment: LDS integer histograms + bbox, fused normalization, single write
__global__ __launch_bounds__(256) void k_accum(const uint4* __restrict__ rec,
                                               const int* __restrict__ start,
                                               float* __restrict__ out) {
  int s = blockIdx.x;
  int beg = start[s], end = start[s + 1];
  int n = end - beg;
  __shared__ unsigned hist[240 + 75];
  __shared__ int bb[4];
  for (int i = threadIdx.x; i < 240 + 75; i += 256) hist[i] = 0;
  if (threadIdx.x == 0) { bb[0] = INT_MAX; bb[1] = INT_MAX; bb[2] = INT_MIN; bb[3] = INT_MIN; }
  __syncthreads();

  for (int i = beg + threadIdx.x; i < end; i += 256) {
    uint4 r = rec[i];
    unsigned p = r.x & 0xFFFFFu;
    int x = (int)(p & 1023u), y = (int)(p >> 10);
    atomicMin(&bb[0], x); atomicMin(&bb[1], y);
    atomicMax(&bb[2], x); atomicMax(&bb[3], y);
    unsigned trip[8];
    trip[0] = (r.x >> 20) & 0x3FFu;
    trip[1] = r.y & 0x3FFu; trip[2] = (r.y >> 10) & 0x3FFu; trip[3] = (r.y >> 20) & 0x3FFu;
    trip[4] = r.z & 0x3FFu; trip[5] = (r.z >> 10) & 0x3FFu; trip[6] = (r.z >> 20) & 0x3FFu;
    trip[7] = r.w & 0x3FFu;
    unsigned cp = r.w >> 10;
    #pragma unroll
    for (int j = 0; j < 8; ++j) {
      unsigned t = trip[j];
      unsigned q2 = t / 100u; unsigned rr = t - 100u*q2;
      unsigned q1 = rr / 10u; unsigned q0 = rr - 10u*q1;
      atomicAdd(&hist[(3*j + 0)*10 + q0], 1u);
      atomicAdd(&hist[(3*j + 1)*10 + q1], 1u);
      atomicAdd(&hist[(3*j + 2)*10 + q2], 1u);
    }
    unsigned c0 = cp % 25u; unsigned rem = cp / 25u;
    unsigned c1 = rem % 25u; unsigned c2 = rem / 25u;
    atomicAdd(&hist[240 + 0*25 + c0], 1u);
    atomicAdd(&hist[240 + 1*25 + c1], 1u);
    atomicAdd(&hist[240 + 2*25 + c2], 1u);
  }
  __syncthreads();

  if (threadIdx.x == 0) {
    out[4*s + 0] = (float)bb[0];
    out[4*s + 1] = (float)bb[1];
    out[4*s + 2] = (float)(bb[2] - bb[0]);
    out[4*s + 3] = (float)(bb[3] - bb[1]);
    out[OUT_SIZE_OFF + s] = (float)n;
  }
  bool ok = n > 0;
  float cden = 3.0f * (float)n, tden = 24.0f * (float)n;
  for (int i = threadIdx.x; i < 240; i += 256)
    out[OUT_TEX_OFF + s*240 + i] = ok ? (float)hist[i] / tden : 0.0f;
  for (int i = threadIdx.x; i < 75; i += 256)
    out[OUT_COLOR_OFF + s*75 + i] = ok ? (float)hist[240 + i] / cden : 0.0f;
}

// ---------------- launch ----------------

extern "C" void kernel_launch(void* const* d_in, const int* in_sizes, int n_in,
                              void* d_out, int out_size, void* d_ws, size_t ws_size,
                              hipStream_t stream) {
  const float* img = (const float*)d_in[0];
  const int*   reg = (const int*)d_in[1];
  float* out = (float*)d_out;

  char* ws = (char*)d_ws;
  size_t off = 0;
  // grot: 6 floats per rotated-grid point (50.4 MB). rec (16.8 MB) aliases it
  // (grot dead after k_sample; rec written by k_binrec).
  float* grot   = (float*)(ws + off); off += (size_t)6 * RA * 4;   off = (off + 255) & ~(size_t)255;
  uint4* rec    = (uint4*)grot;
  // imgrot (25.19 MB); srot (6 planes * NPIX = 25.17 MB) aliases it
  // (imgrot dead after k_gradrot; srot written by k_sample).
  float* imgrot = (float*)(ws + off); off += (size_t)3 * RA * 4;   off = (off + 255) & ~(size_t)255;
  float* srot   = imgrot;
  int*   cnt    = (int*)(ws + off);   off += 5120 * 4;
  int*   start  = (int*)(ws + off);   off += 5008 * 4;
  int*   offs   = (int*)(ws + off);   off += 5008 * 4;
  float* gmm    = (float*)(ws + off); off += 32 * 4;
  float* params = (float*)(ws + off); off += 64 * 4;               off = (off + 255) & ~(size_t)255;
  float* pmin   = (float*)(ws + off); off += (size_t)12 * NBLK_PIX * 4;
  float* pmax   = (float*)(ws + off); off += (size_t)12 * NBLK_PIX * 4;
  (void)ws_size; (void)in_sizes; (void)n_in; (void)out_size;

  double th  = 45.0 * (M_PI / 180.0);
  float cf = (float)cos(th),  sf = (float)sin(th);    // forward +45
  double thb = -45.0 * (M_PI / 180.0);
  float cbk = (float)cos(thb), sbk = (float)sin(thb); // backward -45

  k_zero   <<<20,                256,  0, stream>>>(cnt);
  k_rot    <<<(RA + 255) / 256,  256,  0, stream>>>(img, imgrot, cf, sf);
  k_gradrot<<<(RA + 255) / 256,  256,  0, stream>>>(imgrot, grot);
  k_sample <<<NBLK_PIX,          256,  0, stream>>>(img, grot, reg, cnt, srot, pmin, pmax, cbk, sbk);
  k_reduce <<<12,                256,  0, stream>>>(pmin, pmax, gmm);
  k_params <<<1,                 32,   0, stream>>>(gmm, params);
  k_scan   <<<1,                 1024, 0, stream>>>(cnt, start, offs);
  k_binrec <<<NBLK_PIX,          256,  0, stream>>>(img, srot, reg, params, offs, rec);
  k_accum  <<<NBSEG,             256,  0, stream>>>(rec, start, out);
}

// Round 4
// 362.802 us; speedup vs baseline: 5.0590x; 1.0199x over previous
//
#include <hip/hip_runtime.h>
#include <math.h>
#include <float.h>
#include <limits.h>

// ---------------- problem constants (fixed by setup_inputs) ----------------
#define HH 1024
#define WW 1024
#define NPIX (HH*WW)          // 1048576
#define RH 1449               // ceil(1024*sqrt(2))
#define RW 1449
#define RA (RH*RW)            // 2099601
#define NBSEG 5000
#define START 211             // int((rot_bbox_w - 1024)/2) for 45 deg
#define NBLK_PIX (NPIX/256)   // 4096 (k_binrec grid)
#define NBLK_B   1024         // k_sampleB grid (32x32 tiles)

// output layout (floats, concatenated in return order)
#define OUT_XYWH_OFF  0          // 5000*4
#define OUT_SIZE_OFF  20000      // 5000
#define OUT_COLOR_OFF 25000      // 5000*3*25
#define OUT_TEX_OFF   400000     // 5000*3*8*10
#define OUT_TOTAL     1600000

// ---------------- device helpers ----------------

// 3x3 zero-padded cross-correlation with kx=[[-3,0,3],[10,0,10],[-3,0,3]] and kx^T.
__device__ __forceinline__ void scharr3(const float* __restrict__ base, long plane,
                                        int y, int x, int h, int w,
                                        float g0[3], float g1[3]) {
  #pragma unroll
  for (int c = 0; c < 3; ++c) {
    const float* p = base + (long)c * plane;
    float n[3][3];
    #pragma unroll
    for (int dy = 0; dy < 3; ++dy) {
      int yy = y + dy - 1;
      #pragma unroll
      for (int dx = 0; dx < 3; ++dx) {
        int xx = x + dx - 1;
        n[dy][dx] = (yy >= 0 && yy < h && xx >= 0 && xx < w) ? p[(long)yy * w + xx] : 0.0f;
      }
    }
    g0[c] = -3.0f*n[0][0] + 3.0f*n[0][2] + 10.0f*n[1][0] + 10.0f*n[1][2] - 3.0f*n[2][0] + 3.0f*n[2][2];
    g1[c] = -3.0f*n[0][0] + 10.0f*n[0][1] - 3.0f*n[0][2] + 3.0f*n[2][0] + 10.0f*n[2][1] + 3.0f*n[2][2];
  }
}

// forward map: rotated-grid point -> img coords (k_rotA)
__device__ __forceinline__ void fwdmap(int x, int y, float cf, float sf,
                                       float& sx, float& sy) {
  #pragma clang fp contract(off)
  float dx = (float)x - 724.0f;   // ncx of 1449-grid
  float dy = (float)y - 724.0f;
  sx = cf*dx - sf*dy + 511.5f;    // cx of 1024-grid
  sy = sf*dx + cf*dy + 511.5f;
}

// back map: final pixel -> rotated-grid coords (k_sampleB)
__device__ __forceinline__ void backmap(int x, int y, float cb, float sb,
                                        float& sx, float& sy) {
  #pragma clang fp contract(off)
  float dx = (float)(x + START) - 1024.5f;   // ncx of 2050-grid
  float dy = (float)(y + START) - 1024.5f;
  sx = cb*dx - sb*dy + 724.0f;               // cx of 1449-grid
  sy = sb*dx + cb*dy + 724.0f;
}

// ---------------- kernels ----------------

__global__ __launch_bounds__(256) void k_zero(int* __restrict__ cnt) {
  int i = blockIdx.x * 256 + threadIdx.x;
  if (i < 5120) cnt[i] = 0;
}

// Rotate via LDS-staged img tiles: 32x32 rotated points/block, img bbox <=46x46.
__global__ __launch_bounds__(256) void k_rotA(const float* __restrict__ img,
                                              float* __restrict__ imgrot,
                                              float cf, float sf) {
  __shared__ float tile[3][46 * 47];
  int rx0 = blockIdx.x * 32, ry0 = blockIdx.y * 32;
  int tid = threadIdx.x;

  float sxa, sya, sxb, syb, sxc, syc, sxd, syd;
  fwdmap(rx0,      ry0,      cf, sf, sxa, sya);
  fwdmap(rx0 + 31, ry0,      cf, sf, sxb, syb);
  fwdmap(rx0,      ry0 + 31, cf, sf, sxc, syc);
  fwdmap(rx0 + 31, ry0 + 31, cf, sf, sxd, syd);
  float mnx = fminf(fminf(sxa, sxb), fminf(sxc, sxd));
  float mny = fminf(fminf(sya, syb), fminf(syc, syd));
  int ixlo = max((int)floorf(mnx), 0);
  int iylo = max((int)floorf(mny), 0);

  for (int i = tid; i < 3 * 46 * 46; i += 256) {
    int c = i / (46 * 46); int r = i - c * (46 * 46);
    int ly = r / 46; int lx = r - ly * 46;
    int gx = ixlo + lx, gy = iylo + ly;
    float v = (gx < WW && gy < HH) ? img[c * NPIX + gy * WW + gx] : 0.0f;
    tile[c][ly * 47 + lx] = v;
  }
  __syncthreads();

  int tx = tid & 31, ty = tid >> 5;
  #pragma unroll
  for (int k = 0; k < 4; ++k) {
    int xr = rx0 + tx, yr = ry0 + ty + 8 * k;
    if (xr >= RW || yr >= RH) continue;
    float sx, sy;
    fwdmap(xr, yr, cf, sf, sx, sy);
    bool valid = (sx >= -0.5f) && (sx <= 1023.5f) && (sy >= -0.5f) && (sy <= 1023.5f);
    int ix = min(max((int)rintf(sx), 0), WW - 1);
    int iy = min(max((int)rintf(sy), 0), HH - 1);
    int lx = min(max(ix - ixlo, 0), 45);
    int ly = min(max(iy - iylo, 0), 45);
    int p = yr * RW + xr;
    float v0 = tile[0][ly * 47 + lx];
    float v1 = tile[1][ly * 47 + lx];
    float v2 = tile[2][ly * 47 + lx];
    imgrot[p]          = valid ? v0 : 0.0f;
    imgrot[RA + p]     = valid ? v1 : 0.0f;
    imgrot[2*RA + p]   = valid ? v2 : 0.0f;
  }
}

// Sample + rotated Scharr via LDS-staged imgrot tiles: 32x32 final pixels/block,
// rotated bbox (+halo) <=48x48. Also img-Scharr, 12-map min/max partials,
// segment counts, srot SoA output.
__global__ __launch_bounds__(256) void k_sampleB(const float* __restrict__ img,
                                                 const float* __restrict__ imgrot,
                                                 const int* __restrict__ reg,
                                                 int* __restrict__ cnt,
                                                 float* __restrict__ srot,
                                                 float* __restrict__ pmin,
                                                 float* __restrict__ pmax,
                                                 float cb, float sb) {
  __shared__ float tile[3][48 * 49];
  __shared__ float smn[12][4], smx[12][4];
  int x0 = blockIdx.x * 32, y0 = blockIdx.y * 32;
  int tid = threadIdx.x;

  float sxa, sya, sxb, syb, sxc, syc, sxd, syd;
  backmap(x0,      y0,      cb, sb, sxa, sya);
  backmap(x0 + 31, y0,      cb, sb, sxb, syb);
  backmap(x0,      y0 + 31, cb, sb, sxc, syc);
  backmap(x0 + 31, y0 + 31, cb, sb, sxd, syd);
  float mnx = fminf(fminf(sxa, sxb), fminf(sxc, sxd));
  float mny = fminf(fminf(sya, syb), fminf(syc, syd));
  int ixlo = (int)floorf(mnx) - 1;   // -1 stencil halo
  int iylo = (int)floorf(mny) - 1;

  for (int i = tid; i < 3 * 48 * 48; i += 256) {
    int c = i / (48 * 48); int r = i - c * (48 * 48);
    int ly = r / 48; int lx = r - ly * 48;
    int gx = ixlo + lx, gy = iylo + ly;
    float v = ((unsigned)gx < (unsigned)RW && (unsigned)gy < (unsigned)RH)
              ? imgrot[(long)c * RA + (long)gy * RW + gx] : 0.0f;   // zero-pad matches scharr3
    tile[c][ly * 49 + lx] = v;
  }
  __syncthreads();

  float vmn[12], vmx[12];
  #pragma unroll
  for (int m = 0; m < 12; ++m) { vmn[m] = FLT_MAX; vmx[m] = -FLT_MAX; }

  int tx = tid & 31, ty = tid >> 5;
  #pragma unroll
  for (int k = 0; k < 4; ++k) {
    int x = x0 + tx, y = y0 + ty + 8 * k;
    int p = y * WW + x;
    int s = reg[p];
    if ((unsigned)s < (unsigned)NBSEG) atomicAdd(&cnt[s], 1);

    float a0[3], a1[3];
    scharr3(img, (long)NPIX, y, x, HH, WW, a0, a1);

    float sx, sy;
    backmap(x, y, cb, sb, sx, sy);
    bool valid = (sx >= -0.5f) && (sx <= (float)RW - 0.5f) &&
                 (sy >= -0.5f) && (sy <= (float)RH - 0.5f);
    int ix = min(max((int)rintf(sx), 0), RW - 1);
    int iy = min(max((int)rintf(sy), 0), RH - 1);
    int lx = min(max(ix - ixlo, 1), 46);
    int ly = min(max(iy - iylo, 1), 46);

    float b0[3], b1[3];
    int base = ly * 49 + lx;
    #pragma unroll
    for (int c = 0; c < 3; ++c) {
      const float* t = &tile[c][0];
      float n00 = t[base - 49 - 1], n01 = t[base - 49], n02 = t[base - 49 + 1];
      float n10 = t[base - 1],                           n12 = t[base + 1];
      float n20 = t[base + 49 - 1], n21 = t[base + 49], n22 = t[base + 49 + 1];
      float g0 = -3.0f*n00 + 3.0f*n02 + 10.0f*n10 + 10.0f*n12 - 3.0f*n20 + 3.0f*n22;
      float g1 = -3.0f*n00 + 10.0f*n01 - 3.0f*n02 + 3.0f*n20 + 10.0f*n21 + 3.0f*n22;
      b0[c] = valid ? g0 : 0.0f;
      b1[c] = valid ? g1 : 0.0f;
    }

    #pragma unroll
    for (int c = 0; c < 3; ++c) {
      srot[(2*c)     * NPIX + p] = b0[c];
      srot[(2*c + 1) * NPIX + p] = b1[c];
      vmn[2*c]     = fminf(vmn[2*c],     a0[c]); vmx[2*c]     = fmaxf(vmx[2*c],     a0[c]);
      vmn[2*c + 1] = fminf(vmn[2*c + 1], a1[c]); vmx[2*c + 1] = fmaxf(vmx[2*c + 1], a1[c]);
      vmn[6 + 2*c]     = fminf(vmn[6 + 2*c],     b0[c]); vmx[6 + 2*c]     = fmaxf(vmx[6 + 2*c],     b0[c]);
      vmn[6 + 2*c + 1] = fminf(vmn[6 + 2*c + 1], b1[c]); vmx[6 + 2*c + 1] = fmaxf(vmx[6 + 2*c + 1], b1[c]);
    }
  }

  #pragma unroll
  for (int off = 32; off >= 1; off >>= 1) {
    #pragma unroll
    for (int m = 0; m < 12; ++m) {
      vmn[m] = fminf(vmn[m], __shfl_xor(vmn[m], off));
      vmx[m] = fmaxf(vmx[m], __shfl_xor(vmx[m], off));
    }
  }
  int wv = tid >> 6;
  if ((tid & 63) == 0) {
    #pragma unroll
    for (int m = 0; m < 12; ++m) { smn[m][wv] = vmn[m]; smx[m][wv] = vmx[m]; }
  }
  __syncthreads();
  if (tid < 12) {
    int m = tid;
    float mn = fminf(fminf(smn[m][0], smn[m][1]), fminf(smn[m][2], smn[m][3]));
    float mx = fmaxf(fmaxf(smx[m][0], smx[m][1]), fmaxf(smx[m][2], smx[m][3]));
    int fb = blockIdx.y * gridDim.x + blockIdx.x;
    pmin[m * NBLK_B + fb] = mn;
    pmax[m * NBLK_B + fb] = mx;
  }
}

__global__ __launch_bounds__(256) void k_reduce(const float* __restrict__ pmin,
                                                const float* __restrict__ pmax,
                                                float* __restrict__ gmm) {
  int m = blockIdx.x;   // 0..11
  float mn = FLT_MAX, mx = -FLT_MAX;
  for (int i = threadIdx.x; i < NBLK_B; i += 256) {
    mn = fminf(mn, pmin[m * NBLK_B + i]);
    mx = fmaxf(mx, pmax[m * NBLK_B + i]);
  }
  #pragma unroll
  for (int off = 32; off >= 1; off >>= 1) {
    mn = fminf(mn, __shfl_xor(mn, off));
    mx = fmaxf(mx, __shfl_xor(mx, off));
  }
  __shared__ float smn[4], smx[4];
  int wv = threadIdx.x >> 6;
  if ((threadIdx.x & 63) == 0) { smn[wv] = mn; smx[wv] = mx; }
  __syncthreads();
  if (threadIdx.x == 0) {
    mn = fminf(fminf(smn[0], smn[1]), fminf(smn[2], smn[3]));
    mx = fmaxf(fmaxf(smx[0], smx[1]), fmaxf(smx[2], smx[3]));
    gmm[2*m] = mn; gmm[2*m + 1] = mx;
  }
}

// derive per-map (c,k) hmin & range from the 12 base-map min/max (relu is monotone)
__global__ void k_params(const float* __restrict__ gmm, float* __restrict__ params) {
  int t = threadIdx.x;
  if (t >= 24) return;
  int c = t / 8, k = t % 8;
  int base = (k < 4) ? (2*c + (k & 1)) : (6 + 2*c + (k & 1));
  bool pos = ((k >> 1) & 1) == 0;   // k in {0,1,4,5} -> max(.,0); {2,3,6,7} -> min(.,0)
  float mn = gmm[2*base], mx = gmm[2*base + 1];
  float hmin, hmax;
  if (pos) { hmin = fmaxf(mn, 0.0f); hmax = fmaxf(mx, 0.0f); }
  else     { hmin = fminf(mn, 0.0f); hmax = fminf(mx, 0.0f); }
  params[2*t]     = hmin;
  params[2*t + 1] = hmax - hmin;
}

// exclusive prefix scan of 5000 segment counts -> start[5001], offs (cursors)
__global__ __launch_bounds__(1024) void k_scan(const int* __restrict__ cnt,
                                               int* __restrict__ start,
                                               int* __restrict__ offs) {
  __shared__ int part[1024];
  int t = threadIdx.x;
  int base = t * 5;
  int v[5]; int sum = 0;
  #pragma unroll
  for (int j = 0; j < 5; ++j) {
    v[j] = (base + j < NBSEG) ? cnt[base + j] : 0;
    sum += v[j];
  }
  part[t] = sum;
  __syncthreads();
  #pragma unroll
  for (int d = 1; d < 1024; d <<= 1) {
    int xv = (t >= d) ? part[t - d] : 0;
    __syncthreads();
    part[t] += xv;
    __syncthreads();
  }
  int run = (t > 0) ? part[t - 1] : 0;   // exclusive
  #pragma unroll
  for (int j = 0; j < 5; ++j) {
    int i = base + j;
    if (i <= NBSEG) start[i] = run;
    if (i < NBSEG)  offs[i] = run;
    run += v[j];
  }
}

// per-pixel: compute all bins exactly as reference, pack into uint4, scatter by segment
__global__ __launch_bounds__(256) void k_binrec(const float* __restrict__ img,
                                                const float* __restrict__ srot,
                                                const int* __restrict__ reg,
                                                const float* __restrict__ params,
                                                int* __restrict__ offs,
                                                uint4* __restrict__ rec) {
  int p = blockIdx.x * 256 + threadIdx.x;
  int y = p >> 10, x = p & (WW - 1);
  int s = reg[p];
  if ((unsigned)s >= (unsigned)NBSEG) return;
  float a0[3], a1[3], b0[3], b1[3];
  scharr3(img, (long)NPIX, y, x, HH, WW, a0, a1);
  #pragma unroll
  for (int c = 0; c < 3; ++c) {
    b0[c] = srot[(2*c)     * NPIX + p];
    b1[c] = srot[(2*c + 1) * NPIX + p];
  }

  unsigned q[24];
  #pragma unroll
  for (int c = 0; c < 3; ++c) {
    float gv[2] = { a0[c], a1[c] };
    float rv[2] = { b0[c], b1[c] };
    #pragma unroll
    for (int d = 0; d < 2; ++d) {
      {
        int m = c*8 + d;
        float v = fmaxf(gv[d], 0.0f);
        int qq = (int)(((v - params[2*m]) / params[2*m + 1]) * 9.0f);
        q[m] = (unsigned)min(max(qq, 0), 9);
      }
      {
        int m = c*8 + 2 + d;
        float v = fminf(gv[d], 0.0f);
        int qq = (int)(((v - params[2*m]) / params[2*m + 1]) * 9.0f);
        q[m] = (unsigned)min(max(qq, 0), 9);
      }
      {
        int m = c*8 + 4 + d;
        float v = fmaxf(rv[d], 0.0f);
        int qq = (int)(((v - params[2*m]) / params[2*m + 1]) * 9.0f);
        q[m] = (unsigned)min(max(qq, 0), 9);
      }
      {
        int m = c*8 + 6 + d;
        float v = fminf(rv[d], 0.0f);
        int qq = (int)(((v - params[2*m]) / params[2*m + 1]) * 9.0f);
        q[m] = (unsigned)min(max(qq, 0), 9);
      }
    }
  }
  unsigned qc[3];
  #pragma unroll
  for (int c = 0; c < 3; ++c) {
    int cc = (int)(img[c * NPIX + p] * 24.0f);   // (img*(cb-1)).astype(int32)
    qc[c] = (unsigned)min(max(cc, 0), 24);
  }

  unsigned trip[8];
  #pragma unroll
  for (int j = 0; j < 8; ++j)
    trip[j] = q[3*j] + 10u*q[3*j + 1] + 100u*q[3*j + 2];
  unsigned cp = qc[0] + 25u*qc[1] + 625u*qc[2];

  uint4 r;
  r.x = (unsigned)p | (trip[0] << 20);
  r.y = trip[1] | (trip[2] << 10) | (trip[3] << 20);
  r.z = trip[4] | (trip[5] << 10) | (trip[6] << 20);
  r.w = trip[7] | (cp << 10);

  int pos = atomicAdd(&offs[s], 1);
  rec[pos] = r;
}

// one block per segment: LDS integer histograms + bbox, fused normalization, single write
__global__ __launch_bounds__(256) void k_accum(const uint4* __restrict__ rec,
                                               const int* __restrict__ start,
                                               float* __restrict__ out) {
  int s = blockIdx.x;
  int beg = start[s], end = start[s + 1];
  int n = end - beg;
  __shared__ unsigned hist[240 + 75];
  __shared__ int bb[4];
  for (int i = threadIdx.x; i < 240 + 75; i += 256) hist[i] = 0;
  if (threadIdx.x == 0) { bb[0] = INT_MAX; bb[1] = INT_MAX; bb[2] = INT_MIN; bb[3] = INT_MIN; }
  __syncthreads();

  for (int i = beg + threadIdx.x; i < end; i += 256) {
    uint4 r = rec[i];
    unsigned p = r.x & 0xFFFFFu;
    int x = (int)(p & 1023u), y = (int)(p >> 10);
    atomicMin(&bb[0], x); atomicMin(&bb[1], y);
    atomicMax(&bb[2], x); atomicMax(&bb[3], y);
    unsigned trip[8];
    trip[0] = (r.x >> 20) & 0x3FFu;
    trip[1] = r.y & 0x3FFu; trip[2] = (r.y >> 10) & 0x3FFu; trip[3] = (r.y >> 20) & 0x3FFu;
    trip[4] = r.z & 0x3FFu; trip[5] = (r.z >> 10) & 0x3FFu; trip[6] = (r.z >> 20) & 0x3FFu;
    trip[7] = r.w & 0x3FFu;
    unsigned cp = r.w >> 10;
    #pragma unroll
    for (int j = 0; j < 8; ++j) {
      unsigned t = trip[j];
      unsigned q2 = t / 100u; unsigned rr = t - 100u*q2;
      unsigned q1 = rr / 10u; unsigned q0 = rr - 10u*q1;
      atomicAdd(&hist[(3*j + 0)*10 + q0], 1u);
      atomicAdd(&hist[(3*j + 1)*10 + q1], 1u);
      atomicAdd(&hist[(3*j + 2)*10 + q2], 1u);
    }
    unsigned c0 = cp % 25u; unsigned rem = cp / 25u;
    unsigned c1 = rem % 25u; unsigned c2 = rem / 25u;
    atomicAdd(&hist[240 + 0*25 + c0], 1u);
    atomicAdd(&hist[240 + 1*25 + c1], 1u);
    atomicAdd(&hist[240 + 2*25 + c2], 1u);
  }
  __syncthreads();

  if (threadIdx.x == 0) {
    out[4*s + 0] = (float)bb[0];
    out[4*s + 1] = (float)bb[1];
    out[4*s + 2] = (float)(bb[2] - bb[0]);
    out[4*s + 3] = (float)(bb[3] - bb[1]);
    out[OUT_SIZE_OFF + s] = (float)n;
  }
  bool ok = n > 0;
  float cden = 3.0f * (float)n, tden = 24.0f * (float)n;
  for (int i = threadIdx.x; i < 240; i += 256)
    out[OUT_TEX_OFF + s*240 + i] = ok ? (float)hist[i] / tden : 0.0f;
  for (int i = threadIdx.x; i < 75; i += 256)
    out[OUT_COLOR_OFF + s*75 + i] = ok ? (float)hist[240 + i] / cden : 0.0f;
}

// ---------------- launch ----------------

extern "C" void kernel_launch(void* const* d_in, const int* in_sizes, int n_in,
                              void* d_out, int out_size, void* d_ws, size_t ws_size,
                              hipStream_t stream) {
  const float* img = (const float*)d_in[0];
  const int*   reg = (const int*)d_in[1];
  float* out = (float*)d_out;

  char* ws = (char*)d_ws;
  size_t off = 0;
  // imgrot 25.2 MB; dead after k_sampleB -> rec (16.8 MB) aliases it.
  float* imgrot = (float*)(ws + off); off += (size_t)3 * RA * 4;   off = (off + 255) & ~(size_t)255;
  uint4* rec    = (uint4*)imgrot;
  // srot: 6 planes * NPIX (25.2 MB) — live from k_sampleB through k_binrec.
  float* srot   = (float*)(ws + off); off += (size_t)6 * NPIX * 4; off = (off + 255) & ~(size_t)255;
  int*   cnt    = (int*)(ws + off);   off += 5120 * 4;
  int*   start  = (int*)(ws + off);   off += 5008 * 4;
  int*   offs   = (int*)(ws + off);   off += 5008 * 4;
  float* gmm    = (float*)(ws + off); off += 32 * 4;
  float* params = (float*)(ws + off); off += 64 * 4;               off = (off + 255) & ~(size_t)255;
  float* pmin   = (float*)(ws + off); off += (size_t)12 * NBLK_B * 4;
  float* pmax   = (float*)(ws + off); off += (size_t)12 * NBLK_B * 4;
  (void)ws_size; (void)in_sizes; (void)n_in; (void)out_size;

  double th  = 45.0 * (M_PI / 180.0);
  float cf = (float)cos(th),  sf = (float)sin(th);    // forward +45
  double thb = -45.0 * (M_PI / 180.0);
  float cbk = (float)cos(thb), sbk = (float)sin(thb); // backward -45

  dim3 gA((RW + 31) / 32, (RH + 31) / 32);   // 46 x 46
  dim3 gB(WW / 32, HH / 32);                 // 32 x 32

  k_zero   <<<20,        256,  0, stream>>>(cnt);
  k_rotA   <<<gA,        256,  0, stream>>>(img, imgrot, cf, sf);
  k_sampleB<<<gB,        256,  0, stream>>>(img, imgrot, reg, cnt, srot, pmin, pmax, cbk, sbk);
  k_reduce <<<12,        256,  0, stream>>>(pmin, pmax, gmm);
  k_params <<<1,         32,   0, stream>>>(gmm, params);
  k_scan   <<<1,         1024, 0, stream>>>(cnt, start, offs);
  k_binrec <<<NBLK_PIX,  256,  0, stream>>>(img, srot, reg, params, offs, rec);
  k_accum  <<<NBSEG,     256,  0, stream>>>(rec, start, out);
}

// Round 5
// 319.075 us; speedup vs baseline: 5.7523x; 1.1370x over previous
//
#include <hip/hip_runtime.h>
#include <math.h>
#include <float.h>
#include <limits.h>

// ---------------- problem constants (fixed by setup_inputs) ----------------
#define HH 1024
#define WW 1024
#define NPIX (HH*WW)          // 1048576
#define RH 1449               // ceil(1024*sqrt(2))
#define RW 1449
#define NBSEG 5000
#define START 211             // int((rot_bbox_w - 1024)/2) for 45 deg
#define NBLK_MM 1024          // k_mm grid (4 px/thread)
#define NBLK_PIX 4096         // k_bin grid (1 px/thread)

// output layout (floats, concatenated in return order)
#define OUT_XYWH_OFF  0          // 5000*4
#define OUT_SIZE_OFF  20000      // 5000
#define OUT_COLOR_OFF 25000      // 5000*3*25
#define OUT_TEX_OFF   400000     // 5000*3*8*10
#define OUT_TOTAL     1600000

// ---------------- device helpers ----------------

// 3x3 zero-padded cross-correlation with kx=[[-3,0,3],[10,0,10],[-3,0,3]] and kx^T.
__device__ __forceinline__ void scharr3(const float* __restrict__ base, long plane,
                                        int y, int x, int h, int w,
                                        float g0[3], float g1[3]) {
  #pragma unroll
  for (int c = 0; c < 3; ++c) {
    const float* p = base + (long)c * plane;
    float n[3][3];
    #pragma unroll
    for (int dy = 0; dy < 3; ++dy) {
      int yy = y + dy - 1;
      #pragma unroll
      for (int dx = 0; dx < 3; ++dx) {
        int xx = x + dx - 1;
        n[dy][dx] = (yy >= 0 && yy < h && xx >= 0 && xx < w) ? p[(long)yy * w + xx] : 0.0f;
      }
    }
    g0[c] = -3.0f*n[0][0] + 3.0f*n[0][2] + 10.0f*n[1][0] + 10.0f*n[1][2] - 3.0f*n[2][0] + 3.0f*n[2][2];
    g1[c] = -3.0f*n[0][0] + 10.0f*n[0][1] - 3.0f*n[0][2] + 3.0f*n[2][0] + 10.0f*n[2][1] + 3.0f*n[2][2];
  }
}

// Fused rotate->Scharr->rotate-back at final pixel (y,x): back-map to the 1449^2
// rotated grid, take the 3x3 stencil there, but each stencil tap's value is the
// forward-mapped nearest img sample (what imgrot held) computed on the fly.
// All taps land within ~2.2px of (y,x) in img -> local, L1-served loads.
// Bit-identical to the materialized-imgrot path (same fp expressions, same masks).
__device__ __forceinline__ void grotfused(const float* __restrict__ img, int y, int x,
                                          float cb, float sb, float cf, float sf,
                                          float b0[3], float b1[3]) {
  float sx, sy;
  {
    #pragma clang fp contract(off)
    float dx = (float)(x + START) - 1024.5f;   // ncx of 2050-grid
    float dy = (float)(y + START) - 1024.5f;
    sx = cb*dx - sb*dy + 724.0f;               // cx of 1449-grid
    sy = sb*dx + cb*dy + 724.0f;
  }
  bool valid2 = (sx >= -0.5f) && (sx <= (float)RW - 0.5f) &&
                (sy >= -0.5f) && (sy <= (float)RH - 0.5f);
  int ix = min(max((int)rintf(sx), 0), RW - 1);
  int iy = min(max((int)rintf(sy), 0), RH - 1);

  float nv[3][9];
  #pragma unroll
  for (int dy = 0; dy < 3; ++dy) {
    #pragma unroll
    for (int dx = 0; dx < 3; ++dx) {
      int rx = ix + dx - 1, ry = iy + dy - 1;
      bool inside = ((unsigned)rx < (unsigned)RW) && ((unsigned)ry < (unsigned)RH); // scharr zero-pad
      float fx, fy;
      {
        #pragma clang fp contract(off)
        float ddx = (float)rx - 724.0f;   // ncx of 1449-grid
        float ddy = (float)ry - 724.0f;
        fx = cf*ddx - sf*ddy + 511.5f;    // cx of 1024-grid
        fy = sf*ddx + cf*ddy + 511.5f;
      }
      bool v1 = (fx >= -0.5f) && (fx <= 1023.5f) && (fy >= -0.5f) && (fy <= 1023.5f); // rotate zero-fill
      int jx = min(max((int)rintf(fx), 0), WW - 1);
      int jy = min(max((int)rintf(fy), 0), HH - 1);
      int idx = jy * WW + jx;          // always in-bounds (clamped) -> safe to load
      bool ok = inside && v1;
      int t = dy * 3 + dx;
      nv[0][t] = ok ? img[idx] : 0.0f;
      nv[1][t] = ok ? img[NPIX + idx] : 0.0f;
      nv[2][t] = ok ? img[2*NPIX + idx] : 0.0f;
    }
  }
  #pragma unroll
  for (int c = 0; c < 3; ++c) {
    float g0 = -3.0f*nv[c][0] + 3.0f*nv[c][2] + 10.0f*nv[c][3] + 10.0f*nv[c][5] - 3.0f*nv[c][6] + 3.0f*nv[c][8];
    float g1 = -3.0f*nv[c][0] + 10.0f*nv[c][1] - 3.0f*nv[c][2] + 3.0f*nv[c][6] + 10.0f*nv[c][7] + 3.0f*nv[c][8];
    b0[c] = valid2 ? g0 : 0.0f;
    b1[c] = valid2 ? g1 : 0.0f;
  }
}

// ---------------- kernels ----------------

__global__ __launch_bounds__(256) void k_zero(int* __restrict__ cnt) {
  int i = blockIdx.x * 256 + threadIdx.x;
  if (i < 5120) cnt[i] = 0;
}

// Pass 1: per pixel compute both gradient sets, accumulate 12-map min/max
// (4 px/thread to amortize the block reduction), count segment sizes.
__global__ __launch_bounds__(256) void k_mm(const float* __restrict__ img,
                                            const int* __restrict__ reg,
                                            int* __restrict__ cnt,
                                            float* __restrict__ pmin,
                                            float* __restrict__ pmax,
                                            float cb, float sb, float cf, float sf) {
  int base = blockIdx.x * 256 + threadIdx.x;   // [0, 262144)
  float vmn[12], vmx[12];
  #pragma unroll
  for (int m = 0; m < 12; ++m) { vmn[m] = FLT_MAX; vmx[m] = -FLT_MAX; }

  #pragma unroll
  for (int k = 0; k < 4; ++k) {
    int p = base + k * (NPIX / 4);
    int y = p >> 10, x = p & (WW - 1);
    int s = reg[p];
    if ((unsigned)s < (unsigned)NBSEG) atomicAdd(&cnt[s], 1);

    float a0[3], a1[3], b0[3], b1[3];
    scharr3(img, (long)NPIX, y, x, HH, WW, a0, a1);
    grotfused(img, y, x, cb, sb, cf, sf, b0, b1);

    #pragma unroll
    for (int c = 0; c < 3; ++c) {
      vmn[2*c]     = fminf(vmn[2*c],     a0[c]); vmx[2*c]     = fmaxf(vmx[2*c],     a0[c]);
      vmn[2*c + 1] = fminf(vmn[2*c + 1], a1[c]); vmx[2*c + 1] = fmaxf(vmx[2*c + 1], a1[c]);
      vmn[6 + 2*c]     = fminf(vmn[6 + 2*c],     b0[c]); vmx[6 + 2*c]     = fmaxf(vmx[6 + 2*c],     b0[c]);
      vmn[6 + 2*c + 1] = fminf(vmn[6 + 2*c + 1], b1[c]); vmx[6 + 2*c + 1] = fmaxf(vmx[6 + 2*c + 1], b1[c]);
    }
  }

  #pragma unroll
  for (int off = 32; off >= 1; off >>= 1) {
    #pragma unroll
    for (int m = 0; m < 12; ++m) {
      vmn[m] = fminf(vmn[m], __shfl_xor(vmn[m], off));
      vmx[m] = fmaxf(vmx[m], __shfl_xor(vmx[m], off));
    }
  }
  __shared__ float smn[12][4], smx[12][4];
  int wv = threadIdx.x >> 6;
  if ((threadIdx.x & 63) == 0) {
    #pragma unroll
    for (int m = 0; m < 12; ++m) { smn[m][wv] = vmn[m]; smx[m][wv] = vmx[m]; }
  }
  __syncthreads();
  if (threadIdx.x < 12) {
    int m = threadIdx.x;
    float mn = fminf(fminf(smn[m][0], smn[m][1]), fminf(smn[m][2], smn[m][3]));
    float mx = fmaxf(fmaxf(smx[m][0], smx[m][1]), fmaxf(smx[m][2], smx[m][3]));
    pmin[m * NBLK_MM + blockIdx.x] = mn;
    pmax[m * NBLK_MM + blockIdx.x] = mx;
  }
}

// Fused: blocks 0..11 reduce one map's partials -> gmm; block 12 prefix-scans counts.
__global__ __launch_bounds__(1024) void k_redscan(const float* __restrict__ pmin,
                                                  const float* __restrict__ pmax,
                                                  const int* __restrict__ cnt,
                                                  float* __restrict__ gmm,
                                                  int* __restrict__ start,
                                                  int* __restrict__ offs) {
  int t = threadIdx.x;
  if (blockIdx.x < 12) {
    int m = blockIdx.x;
    float mn = pmin[m * NBLK_MM + t];
    float mx = pmax[m * NBLK_MM + t];
    #pragma unroll
    for (int off = 32; off >= 1; off >>= 1) {
      mn = fminf(mn, __shfl_xor(mn, off));
      mx = fmaxf(mx, __shfl_xor(mx, off));
    }
    __shared__ float smn[16], smx[16];
    int wv = t >> 6;
    if ((t & 63) == 0) { smn[wv] = mn; smx[wv] = mx; }
    __syncthreads();
    if (t == 0) {
      #pragma unroll
      for (int i = 1; i < 16; ++i) { mn = fminf(mn, smn[i]); mx = fmaxf(mx, smx[i]); }
      gmm[2*m] = mn; gmm[2*m + 1] = mx;
    }
    return;
  }
  // block 12: exclusive scan of 5000 counts
  __shared__ int part[1024];
  int base = t * 5;
  int v[5]; int sum = 0;
  #pragma unroll
  for (int j = 0; j < 5; ++j) {
    v[j] = (base + j < NBSEG) ? cnt[base + j] : 0;
    sum += v[j];
  }
  part[t] = sum;
  __syncthreads();
  #pragma unroll
  for (int d = 1; d < 1024; d <<= 1) {
    int xv = (t >= d) ? part[t - d] : 0;
    __syncthreads();
    part[t] += xv;
    __syncthreads();
  }
  int run = (t > 0) ? part[t - 1] : 0;   // exclusive
  #pragma unroll
  for (int j = 0; j < 5; ++j) {
    int i = base + j;
    if (i <= NBSEG) start[i] = run;
    if (i < NBSEG)  offs[i] = run;
    run += v[j];
  }
}

// Pass 2: recompute gradients, quantize all 27 bins (params derived from gmm
// in-block), pack into uint4, scatter by segment cursor.
__global__ __launch_bounds__(256) void k_bin(const float* __restrict__ img,
                                             const int* __restrict__ reg,
                                             const float* __restrict__ gmm,
                                             int* __restrict__ offs,
                                             uint4* __restrict__ rec,
                                             float cb, float sb, float cf, float sf) {
  __shared__ float params[48];
  if (threadIdx.x < 24) {
    int t = threadIdx.x;
    int c = t / 8, k = t % 8;
    int b = (k < 4) ? (2*c + (k & 1)) : (6 + 2*c + (k & 1));
    bool pos = ((k >> 1) & 1) == 0;   // k in {0,1,4,5} -> max(.,0); {2,3,6,7} -> min(.,0)
    float mn = gmm[2*b], mx = gmm[2*b + 1];
    float hmin, hmax;
    if (pos) { hmin = fmaxf(mn, 0.0f); hmax = fmaxf(mx, 0.0f); }
    else     { hmin = fminf(mn, 0.0f); hmax = fminf(mx, 0.0f); }
    params[2*t]     = hmin;
    params[2*t + 1] = hmax - hmin;
  }
  __syncthreads();

  int p = blockIdx.x * 256 + threadIdx.x;
  int y = p >> 10, x = p & (WW - 1);
  int s = reg[p];
  if ((unsigned)s >= (unsigned)NBSEG) return;

  float a0[3], a1[3], b0[3], b1[3];
  scharr3(img, (long)NPIX, y, x, HH, WW, a0, a1);
  grotfused(img, y, x, cb, sb, cf, sf, b0, b1);

  unsigned q[24];
  #pragma unroll
  for (int c = 0; c < 3; ++c) {
    float gv[2] = { a0[c], a1[c] };
    float rv[2] = { b0[c], b1[c] };
    #pragma unroll
    for (int d = 0; d < 2; ++d) {
      {
        int m = c*8 + d;
        float v = fmaxf(gv[d], 0.0f);
        int qq = (int)(((v - params[2*m]) / params[2*m + 1]) * 9.0f);
        q[m] = (unsigned)min(max(qq, 0), 9);
      }
      {
        int m = c*8 + 2 + d;
        float v = fminf(gv[d], 0.0f);
        int qq = (int)(((v - params[2*m]) / params[2*m + 1]) * 9.0f);
        q[m] = (unsigned)min(max(qq, 0), 9);
      }
      {
        int m = c*8 + 4 + d;
        float v = fmaxf(rv[d], 0.0f);
        int qq = (int)(((v - params[2*m]) / params[2*m + 1]) * 9.0f);
        q[m] = (unsigned)min(max(qq, 0), 9);
      }
      {
        int m = c*8 + 6 + d;
        float v = fminf(rv[d], 0.0f);
        int qq = (int)(((v - params[2*m]) / params[2*m + 1]) * 9.0f);
        q[m] = (unsigned)min(max(qq, 0), 9);
      }
    }
  }
  unsigned qc[3];
  #pragma unroll
  for (int c = 0; c < 3; ++c) {
    int cc = (int)(img[c * NPIX + p] * 24.0f);   // (img*(cb-1)).astype(int32)
    qc[c] = (unsigned)min(max(cc, 0), 24);
  }

  unsigned trip[8];
  #pragma unroll
  for (int j = 0; j < 8; ++j)
    trip[j] = q[3*j] + 10u*q[3*j + 1] + 100u*q[3*j + 2];
  unsigned cp = qc[0] + 25u*qc[1] + 625u*qc[2];

  uint4 r;
  r.x = (unsigned)p | (trip[0] << 20);
  r.y = trip[1] | (trip[2] << 10) | (trip[3] << 20);
  r.z = trip[4] | (trip[5] << 10) | (trip[6] << 20);
  r.w = trip[7] | (cp << 10);

  int pos = atomicAdd(&offs[s], 1);
  rec[pos] = r;
}

// one block per segment: LDS integer histograms + bbox, fused normalization, single write
__global__ __launch_bounds__(256) void k_accum(const uint4* __restrict__ rec,
                                               const int* __restrict__ start,
                                               float* __restrict__ out) {
  int s = blockIdx.x;
  int beg = start[s], end = start[s + 1];
  int n = end - beg;
  __shared__ unsigned hist[240 + 75];
  __shared__ int bb[4];
  for (int i = threadIdx.x; i < 240 + 75; i += 256) hist[i] = 0;
  if (threadIdx.x == 0) { bb[0] = INT_MAX; bb[1] = INT_MAX; bb[2] = INT_MIN; bb[3] = INT_MIN; }
  __syncthreads();

  for (int i = beg + threadIdx.x; i < end; i += 256) {
    uint4 r = rec[i];
    unsigned p = r.x & 0xFFFFFu;
    int x = (int)(p & 1023u), y = (int)(p >> 10);
    atomicMin(&bb[0], x); atomicMin(&bb[1], y);
    atomicMax(&bb[2], x); atomicMax(&bb[3], y);
    unsigned trip[8];
    trip[0] = (r.x >> 20) & 0x3FFu;
    trip[1] = r.y & 0x3FFu; trip[2] = (r.y >> 10) & 0x3FFu; trip[3] = (r.y >> 20) & 0x3FFu;
    trip[4] = r.z & 0x3FFu; trip[5] = (r.z >> 10) & 0x3FFu; trip[6] = (r.z >> 20) & 0x3FFu;
    trip[7] = r.w & 0x3FFu;
    unsigned cp = r.w >> 10;
    #pragma unroll
    for (int j = 0; j < 8; ++j) {
      unsigned t = trip[j];
      unsigned q2 = t / 100u; unsigned rr = t - 100u*q2;
      unsigned q1 = rr / 10u; unsigned q0 = rr - 10u*q1;
      atomicAdd(&hist[(3*j + 0)*10 + q0], 1u);
      atomicAdd(&hist[(3*j + 1)*10 + q1], 1u);
      atomicAdd(&hist[(3*j + 2)*10 + q2], 1u);
    }
    unsigned c0 = cp % 25u; unsigned rem = cp / 25u;
    unsigned c1 = rem % 25u; unsigned c2 = rem / 25u;
    atomicAdd(&hist[240 + 0*25 + c0], 1u);
    atomicAdd(&hist[240 + 1*25 + c1], 1u);
    atomicAdd(&hist[240 + 2*25 + c2], 1u);
  }
  __syncthreads();

  if (threadIdx.x == 0) {
    out[4*s + 0] = (float)bb[0];
    out[4*s + 1] = (float)bb[1];
    out[4*s + 2] = (float)(bb[2] - bb[0]);
    out[4*s + 3] = (float)(bb[3] - bb[1]);
    out[OUT_SIZE_OFF + s] = (float)n;
  }
  bool ok = n > 0;
  float cden = 3.0f * (float)n, tden = 24.0f * (float)n;
  for (int i = threadIdx.x; i < 240; i += 256)
    out[OUT_TEX_OFF + s*240 + i] = ok ? (float)hist[i] / tden : 0.0f;
  for (int i = threadIdx.x; i < 75; i += 256)
    out[OUT_COLOR_OFF + s*75 + i] = ok ? (float)hist[240 + i] / cden : 0.0f;
}

// ---------------- launch ----------------

extern "C" void kernel_launch(void* const* d_in, const int* in_sizes, int n_in,
                              void* d_out, int out_size, void* d_ws, size_t ws_size,
                              hipStream_t stream) {
  const float* img = (const float*)d_in[0];
  const int*   reg = (const int*)d_in[1];
  float* out = (float*)d_out;

  char* ws = (char*)d_ws;
  size_t off = 0;
  uint4* rec    = (uint4*)(ws + off); off += (size_t)NPIX * 16;     off = (off + 255) & ~(size_t)255;
  int*   cnt    = (int*)(ws + off);   off += 5120 * 4;
  int*   start  = (int*)(ws + off);   off += 5008 * 4;
  int*   offs   = (int*)(ws + off);   off += 5008 * 4;
  float* gmm    = (float*)(ws + off); off += 32 * 4;                off = (off + 255) & ~(size_t)255;
  float* pmin   = (float*)(ws + off); off += (size_t)12 * NBLK_MM * 4;
  float* pmax   = (float*)(ws + off); off += (size_t)12 * NBLK_MM * 4;
  (void)ws_size; (void)in_sizes; (void)n_in; (void)out_size;

  double th  = 45.0 * (M_PI / 180.0);
  float cf = (float)cos(th),  sf = (float)sin(th);    // forward +45
  double thb = -45.0 * (M_PI / 180.0);
  float cbk = (float)cos(thb), sbk = (float)sin(thb); // backward -45

  k_zero   <<<20,        256,  0, stream>>>(cnt);
  k_mm     <<<NBLK_MM,   256,  0, stream>>>(img, reg, cnt, pmin, pmax, cbk, sbk, cf, sf);
  k_redscan<<<13,        1024, 0, stream>>>(pmin, pmax, cnt, gmm, start, offs);
  k_bin    <<<NBLK_PIX,  256,  0, stream>>>(img, reg, gmm, offs, rec, cbk, sbk, cf, sf);
  k_accum  <<<NBSEG,     256,  0, stream>>>(rec, start, out);
}

// Round 6
// 294.231 us; speedup vs baseline: 6.2380x; 1.0844x over previous
//
#include <hip/hip_runtime.h>
#include <math.h>
#include <float.h>
#include <limits.h>

// ---------------- problem constants (fixed by setup_inputs) ----------------
#define HH 1024
#define WW 1024
#define NPIX (HH*WW)          // 1048576
#define RH 1449               // ceil(1024*sqrt(2))
#define RW 1449
#define NBSEG 5000
#define START 211             // int((rot_bbox_w - 1024)/2) for 45 deg
#define NBLK_MM 1024          // k_mm grid (4 px/thread)
#define NBLK_PIX 4096         // k_bin grid (1 px/thread)

// output layout (floats, concatenated in return order)
#define OUT_XYWH_OFF  0          // 5000*4
#define OUT_SIZE_OFF  20000      // 5000
#define OUT_COLOR_OFF 25000      // 5000*3*25
#define OUT_TEX_OFF   400000     // 5000*3*8*10
#define OUT_TOTAL     1600000

// ---------------- kernels ----------------

__global__ __launch_bounds__(256) void k_zero(int* __restrict__ cnt) {
  int i = blockIdx.x * 256 + threadIdx.x;
  if (i < 5120) cnt[i] = 0;
}

// Pass 1: per pixel compute both gradient sets (per-channel to cap VGPRs),
// store them as 3 float4 planes for k_bin, accumulate 12-map min/max
// (4 px/thread amortizes the block reduction), count segment sizes.
__global__ __launch_bounds__(256, 5) void k_mm(const float* __restrict__ img,
                                               const int* __restrict__ reg,
                                               int* __restrict__ cnt,
                                               float4* __restrict__ grad4,
                                               float* __restrict__ pmin,
                                               float* __restrict__ pmax,
                                               float cb, float sb, float cf, float sf) {
  int tbase = blockIdx.x * 256 + threadIdx.x;   // [0, 262144)
  float vmn[12], vmx[12];
  #pragma unroll
  for (int m = 0; m < 12; ++m) { vmn[m] = FLT_MAX; vmx[m] = -FLT_MAX; }

  #pragma unroll
  for (int k = 0; k < 4; ++k) {
    int p = tbase + k * (NPIX / 4);
    int y = p >> 10, x = p & (WW - 1);
    int s = reg[p];
    if ((unsigned)s < (unsigned)NBSEG) atomicAdd(&cnt[s], 1);

    // ---- rot-tap geometry (shared across channels): 9 indices + validity mask
    float sx, sy;
    {
      #pragma clang fp contract(off)
      float dx = (float)(x + START) - 1024.5f;   // ncx of 2050-grid
      float dy = (float)(y + START) - 1024.5f;
      sx = cb*dx - sb*dy + 724.0f;               // cx of 1449-grid
      sy = sb*dx + cb*dy + 724.0f;
    }
    bool valid2 = (sx >= -0.5f) && (sx <= (float)RW - 0.5f) &&
                  (sy >= -0.5f) && (sy <= (float)RH - 0.5f);
    int ix = min(max((int)rintf(sx), 0), RW - 1);
    int iy = min(max((int)rintf(sy), 0), RH - 1);

    int idxs[9];
    unsigned okm = 0;
    #pragma unroll
    for (int t = 0; t < 9; ++t) {
      int rx = ix + (t % 3) - 1, ry = iy + (t / 3) - 1;
      bool inside = ((unsigned)rx < (unsigned)RW) && ((unsigned)ry < (unsigned)RH);
      float fx, fy;
      {
        #pragma clang fp contract(off)
        float ddx = (float)rx - 724.0f;   // ncx of 1449-grid
        float ddy = (float)ry - 724.0f;
        fx = cf*ddx - sf*ddy + 511.5f;    // cx of 1024-grid
        fy = sf*ddx + cf*ddy + 511.5f;
      }
      bool v1 = (fx >= -0.5f) && (fx <= 1023.5f) && (fy >= -0.5f) && (fy <= 1023.5f);
      int jx = min(max((int)rintf(fx), 0), WW - 1);
      int jy = min(max((int)rintf(fy), 0), HH - 1);
      idxs[t] = jy * WW + jx;
      okm |= ((unsigned)(inside && v1)) << t;
    }

    bool interior = (x >= 1) && (x <= WW - 2) && (y >= 1) && (y <= HH - 2);

    #pragma unroll
    for (int c = 0; c < 3; ++c) {
      const float* pp = img + (long)c * NPIX;
      float n00, n01, n02, n10, n12, n20, n21, n22;
      if (interior) {
        const float* q = pp + p;
        n00 = q[-WW - 1]; n01 = q[-WW]; n02 = q[-WW + 1];
        n10 = q[-1];                    n12 = q[1];
        n20 = q[WW - 1];  n21 = q[WW];  n22 = q[WW + 1];
      } else {
        bool yu = y > 0, yd = y < HH - 1, xl = x > 0, xr = x < WW - 1;
        n00 = (yu && xl) ? pp[p - WW - 1] : 0.0f;
        n01 = (yu)       ? pp[p - WW]     : 0.0f;
        n02 = (yu && xr) ? pp[p - WW + 1] : 0.0f;
        n10 = (xl)       ? pp[p - 1]      : 0.0f;
        n12 = (xr)       ? pp[p + 1]      : 0.0f;
        n20 = (yd && xl) ? pp[p + WW - 1] : 0.0f;
        n21 = (yd)       ? pp[p + WW]     : 0.0f;
        n22 = (yd && xr) ? pp[p + WW + 1] : 0.0f;
      }
      float a0 = -3.0f*n00 + 3.0f*n02 + 10.0f*n10 + 10.0f*n12 - 3.0f*n20 + 3.0f*n22;
      float a1 = -3.0f*n00 + 10.0f*n01 - 3.0f*n02 + 3.0f*n20 + 10.0f*n21 + 3.0f*n22;

      float m0, m1, m2, m3, m4, m5, m6, m7, m8;
      m0 = (okm & 1u)   ? pp[idxs[0]] : 0.0f;
      m1 = (okm & 2u)   ? pp[idxs[1]] : 0.0f;
      m2 = (okm & 4u)   ? pp[idxs[2]] : 0.0f;
      m3 = (okm & 8u)   ? pp[idxs[3]] : 0.0f;
      m4 = (okm & 16u)  ? pp[idxs[4]] : 0.0f;
      m5 = (okm & 32u)  ? pp[idxs[5]] : 0.0f;
      m6 = (okm & 64u)  ? pp[idxs[6]] : 0.0f;
      m7 = (okm & 128u) ? pp[idxs[7]] : 0.0f;
      m8 = (okm & 256u) ? pp[idxs[8]] : 0.0f;
      (void)m4;
      float r0 = -3.0f*m0 + 3.0f*m2 + 10.0f*m3 + 10.0f*m5 - 3.0f*m6 + 3.0f*m8;
      float r1 = -3.0f*m0 + 10.0f*m1 - 3.0f*m2 + 3.0f*m6 + 10.0f*m7 + 3.0f*m8;
      float b0 = valid2 ? r0 : 0.0f;
      float b1 = valid2 ? r1 : 0.0f;

      grad4[(long)c * NPIX + p] = make_float4(a0, a1, b0, b1);

      vmn[2*c]     = fminf(vmn[2*c],     a0); vmx[2*c]     = fmaxf(vmx[2*c],     a0);
      vmn[2*c + 1] = fminf(vmn[2*c + 1], a1); vmx[2*c + 1] = fmaxf(vmx[2*c + 1], a1);
      vmn[6 + 2*c]     = fminf(vmn[6 + 2*c],     b0); vmx[6 + 2*c]     = fmaxf(vmx[6 + 2*c],     b0);
      vmn[6 + 2*c + 1] = fminf(vmn[6 + 2*c + 1], b1); vmx[6 + 2*c + 1] = fmaxf(vmx[6 + 2*c + 1], b1);
    }
  }

  #pragma unroll
  for (int off = 32; off >= 1; off >>= 1) {
    #pragma unroll
    for (int m = 0; m < 12; ++m) {
      vmn[m] = fminf(vmn[m], __shfl_xor(vmn[m], off));
      vmx[m] = fmaxf(vmx[m], __shfl_xor(vmx[m], off));
    }
  }
  __shared__ float smn[12][4], smx[12][4];
  int wv = threadIdx.x >> 6;
  if ((threadIdx.x & 63) == 0) {
    #pragma unroll
    for (int m = 0; m < 12; ++m) { smn[m][wv] = vmn[m]; smx[m][wv] = vmx[m]; }
  }
  __syncthreads();
  if (threadIdx.x < 12) {
    int m = threadIdx.x;
    float mn = fminf(fminf(smn[m][0], smn[m][1]), fminf(smn[m][2], smn[m][3]));
    float mx = fmaxf(fmaxf(smx[m][0], smx[m][1]), fmaxf(smx[m][2], smx[m][3]));
    pmin[m * NBLK_MM + blockIdx.x] = mn;
    pmax[m * NBLK_MM + blockIdx.x] = mx;
  }
}

// Fused: blocks 0..11 reduce one map's partials -> gmm; block 12 prefix-scans counts.
__global__ __launch_bounds__(1024) void k_redscan(const float* __restrict__ pmin,
                                                  const float* __restrict__ pmax,
                                                  const int* __restrict__ cnt,
                                                  float* __restrict__ gmm,
                                                  int* __restrict__ start,
                                                  int* __restrict__ offs) {
  int t = threadIdx.x;
  if (blockIdx.x < 12) {
    int m = blockIdx.x;
    float mn = pmin[m * NBLK_MM + t];
    float mx = pmax[m * NBLK_MM + t];
    #pragma unroll
    for (int off = 32; off >= 1; off >>= 1) {
      mn = fminf(mn, __shfl_xor(mn, off));
      mx = fmaxf(mx, __shfl_xor(mx, off));
    }
    __shared__ float smn[16], smx[16];
    int wv = t >> 6;
    if ((t & 63) == 0) { smn[wv] = mn; smx[wv] = mx; }
    __syncthreads();
    if (t == 0) {
      #pragma unroll
      for (int i = 1; i < 16; ++i) { mn = fminf(mn, smn[i]); mx = fmaxf(mx, smx[i]); }
      gmm[2*m] = mn; gmm[2*m + 1] = mx;
    }
    return;
  }
  // block 12: exclusive scan of 5000 counts
  __shared__ int part[1024];
  int base = t * 5;
  int v[5]; int sum = 0;
  #pragma unroll
  for (int j = 0; j < 5; ++j) {
    v[j] = (base + j < NBSEG) ? cnt[base + j] : 0;
    sum += v[j];
  }
  part[t] = sum;
  __syncthreads();
  #pragma unroll
  for (int d = 1; d < 1024; d <<= 1) {
    int xv = (t >= d) ? part[t - d] : 0;
    __syncthreads();
    part[t] += xv;
    __syncthreads();
  }
  int run = (t > 0) ? part[t - 1] : 0;   // exclusive
  #pragma unroll
  for (int j = 0; j < 5; ++j) {
    int i = base + j;
    if (i <= NBSEG) start[i] = run;
    if (i < NBSEG)  offs[i] = run;
    run += v[j];
  }
}

// Pass 2: load stored gradients, quantize all 27 bins (params derived from gmm
// in-block), pack into uint4, scatter by segment cursor.
__global__ __launch_bounds__(256) void k_bin(const float* __restrict__ img,
                                             const int* __restrict__ reg,
                                             const float* __restrict__ gmm,
                                             const float4* __restrict__ grad4,
                                             int* __restrict__ offs,
                                             uint4* __restrict__ rec) {
  __shared__ float params[48];
  if (threadIdx.x < 24) {
    int t = threadIdx.x;
    int c = t / 8, k = t % 8;
    int b = (k < 4) ? (2*c + (k & 1)) : (6 + 2*c + (k & 1));
    bool pos = ((k >> 1) & 1) == 0;   // k in {0,1,4,5} -> max(.,0); {2,3,6,7} -> min(.,0)
    float mn = gmm[2*b], mx = gmm[2*b + 1];
    float hmin, hmax;
    if (pos) { hmin = fmaxf(mn, 0.0f); hmax = fmaxf(mx, 0.0f); }
    else     { hmin = fminf(mn, 0.0f); hmax = fminf(mx, 0.0f); }
    params[2*t]     = hmin;
    params[2*t + 1] = hmax - hmin;
  }
  __syncthreads();

  int p = blockIdx.x * 256 + threadIdx.x;
  int s = reg[p];
  if ((unsigned)s >= (unsigned)NBSEG) return;

  unsigned q[24];
  #pragma unroll
  for (int c = 0; c < 3; ++c) {
    float4 g = grad4[(long)c * NPIX + p];
    float gv[2] = { g.x, g.y };
    float rv[2] = { g.z, g.w };
    #pragma unroll
    for (int d = 0; d < 2; ++d) {
      {
        int m = c*8 + d;
        float v = fmaxf(gv[d], 0.0f);
        int qq = (int)(((v - params[2*m]) / params[2*m + 1]) * 9.0f);
        q[m] = (unsigned)min(max(qq, 0), 9);
      }
      {
        int m = c*8 + 2 + d;
        float v = fminf(gv[d], 0.0f);
        int qq = (int)(((v - params[2*m]) / params[2*m + 1]) * 9.0f);
        q[m] = (unsigned)min(max(qq, 0), 9);
      }
      {
        int m = c*8 + 4 + d;
        float v = fmaxf(rv[d], 0.0f);
        int qq = (int)(((v - params[2*m]) / params[2*m + 1]) * 9.0f);
        q[m] = (unsigned)min(max(qq, 0), 9);
      }
      {
        int m = c*8 + 6 + d;
        float v = fminf(rv[d], 0.0f);
        int qq = (int)(((v - params[2*m]) / params[2*m + 1]) * 9.0f);
        q[m] = (unsigned)min(max(qq, 0), 9);
      }
    }
  }
  unsigned qc[3];
  #pragma unroll
  for (int c = 0; c < 3; ++c) {
    int cc = (int)(img[c * NPIX + p] * 24.0f);   // (img*(cb-1)).astype(int32)
    qc[c] = (unsigned)min(max(cc, 0), 24);
  }

  unsigned trip[8];
  #pragma unroll
  for (int j = 0; j < 8; ++j)
    trip[j] = q[3*j] + 10u*q[3*j + 1] + 100u*q[3*j + 2];
  unsigned cp = qc[0] + 25u*qc[1] + 625u*qc[2];

  uint4 r;
  r.x = (unsigned)p | (trip[0] << 20);
  r.y = trip[1] | (trip[2] << 10) | (trip[3] << 20);
  r.z = trip[4] | (trip[5] << 10) | (trip[6] << 20);
  r.w = trip[7] | (cp << 10);

  int pos = atomicAdd(&offs[s], 1);
  rec[pos] = r;
}

// one block per segment: LDS integer histograms + bbox, fused normalization, single write
__global__ __launch_bounds__(256) void k_accum(const uint4* __restrict__ rec,
                                               const int* __restrict__ start,
                                               float* __restrict__ out) {
  int s = blockIdx.x;
  int beg = start[s], end = start[s + 1];
  int n = end - beg;
  __shared__ unsigned hist[240 + 75];
  __shared__ int bb[4];
  for (int i = threadIdx.x; i < 240 + 75; i += 256) hist[i] = 0;
  if (threadIdx.x == 0) { bb[0] = INT_MAX; bb[1] = INT_MAX; bb[2] = INT_MIN; bb[3] = INT_MIN; }
  __syncthreads();

  for (int i = beg + threadIdx.x; i < end; i += 256) {
    uint4 r = rec[i];
    unsigned p = r.x & 0xFFFFFu;
    int x = (int)(p & 1023u), y = (int)(p >> 10);
    atomicMin(&bb[0], x); atomicMin(&bb[1], y);
    atomicMax(&bb[2], x); atomicMax(&bb[3], y);
    unsigned trip[8];
    trip[0] = (r.x >> 20) & 0x3FFu;
    trip[1] = r.y & 0x3FFu; trip[2] = (r.y >> 10) & 0x3FFu; trip[3] = (r.y >> 20) & 0x3FFu;
    trip[4] = r.z & 0x3FFu; trip[5] = (r.z >> 10) & 0x3FFu; trip[6] = (r.z >> 20) & 0x3FFu;
    trip[7] = r.w & 0x3FFu;
    unsigned cp = r.w >> 10;
    #pragma unroll
    for (int j = 0; j < 8; ++j) {
      unsigned t = trip[j];
      unsigned q2 = t / 100u; unsigned rr = t - 100u*q2;
      unsigned q1 = rr / 10u; unsigned q0 = rr - 10u*q1;
      atomicAdd(&hist[(3*j + 0)*10 + q0], 1u);
      atomicAdd(&hist[(3*j + 1)*10 + q1], 1u);
      atomicAdd(&hist[(3*j + 2)*10 + q2], 1u);
    }
    unsigned c0 = cp % 25u; unsigned rem = cp / 25u;
    unsigned c1 = rem % 25u; unsigned c2 = rem / 25u;
    atomicAdd(&hist[240 + 0*25 + c0], 1u);
    atomicAdd(&hist[240 + 1*25 + c1], 1u);
    atomicAdd(&hist[240 + 2*25 + c2], 1u);
  }
  __syncthreads();

  if (threadIdx.x == 0) {
    out[4*s + 0] = (float)bb[0];
    out[4*s + 1] = (float)bb[1];
    out[4*s + 2] = (float)(bb[2] - bb[0]);
    out[4*s + 3] = (float)(bb[3] - bb[1]);
    out[OUT_SIZE_OFF + s] = (float)n;
  }
  bool ok = n > 0;
  float cden = 3.0f * (float)n, tden = 24.0f * (float)n;
  for (int i = threadIdx.x; i < 240; i += 256)
    out[OUT_TEX_OFF + s*240 + i] = ok ? (float)hist[i] / tden : 0.0f;
  for (int i = threadIdx.x; i < 75; i += 256)
    out[OUT_COLOR_OFF + s*75 + i] = ok ? (float)hist[240 + i] / cden : 0.0f;
}

// ---------------- launch ----------------

extern "C" void kernel_launch(void* const* d_in, const int* in_sizes, int n_in,
                              void* d_out, int out_size, void* d_ws, size_t ws_size,
                              hipStream_t stream) {
  const float* img = (const float*)d_in[0];
  const int*   reg = (const int*)d_in[1];
  float* out = (float*)d_out;

  char* ws = (char*)d_ws;
  size_t off = 0;
  float4* grad4 = (float4*)(ws + off); off += (size_t)3 * NPIX * 16;  off = (off + 255) & ~(size_t)255;
  uint4*  rec   = (uint4*)(ws + off);  off += (size_t)NPIX * 16;      off = (off + 255) & ~(size_t)255;
  int*    cnt   = (int*)(ws + off);    off += 5120 * 4;
  int*    start = (int*)(ws + off);    off += 5008 * 4;
  int*    offs  = (int*)(ws + off);    off += 5008 * 4;
  float*  gmm   = (float*)(ws + off);  off += 32 * 4;                 off = (off + 255) & ~(size_t)255;
  float*  pmin  = (float*)(ws + off);  off += (size_t)12 * NBLK_MM * 4;
  float*  pmax  = (float*)(ws + off);  off += (size_t)12 * NBLK_MM * 4;
  (void)ws_size; (void)in_sizes; (void)n_in; (void)out_size;

  double th  = 45.0 * (M_PI / 180.0);
  float cf = (float)cos(th),  sf = (float)sin(th);    // forward +45
  double thb = -45.0 * (M_PI / 180.0);
  float cbk = (float)cos(thb), sbk = (float)sin(thb); // backward -45

  k_zero   <<<20,        256,  0, stream>>>(cnt);
  k_mm     <<<NBLK_MM,   256,  0, stream>>>(img, reg, cnt, grad4, pmin, pmax, cbk, sbk, cf, sf);
  k_redscan<<<13,        1024, 0, stream>>>(pmin, pmax, cnt, gmm, start, offs);
  k_bin    <<<NBLK_PIX,  256,  0, stream>>>(img, reg, gmm, grad4, offs, rec);
  k_accum  <<<NBSEG,     256,  0, stream>>>(rec, start, out);
}

// Round 7
// 271.662 us; speedup vs baseline: 6.7562x; 1.0831x over previous
//
#include <hip/hip_runtime.h>
#include <math.h>
#include <float.h>
#include <limits.h>

// ---------------- problem constants (fixed by setup_inputs) ----------------
#define HH 1024
#define WW 1024
#define NPIX (HH*WW)          // 1048576
#define RH 1449               // ceil(1024*sqrt(2))
#define RW 1449
#define NBSEG 5000
#define START 211             // int((rot_bbox_w - 1024)/2) for 45 deg
#define NBLK_MM 2048          // k_mm grid (2 px/thread)

// output layout (floats, concatenated in return order)
#define OUT_XYWH_OFF  0          // 5000*4
#define OUT_SIZE_OFF  20000      // 5000
#define OUT_COLOR_OFF 25000      // 5000*3*25
#define OUT_TEX_OFF   400000     // 5000*3*8*10
#define OUT_TOTAL     1600000

// ---------------- kernels ----------------

__global__ __launch_bounds__(256) void k_zero(int* __restrict__ cnt) {
  int i = blockIdx.x * 256 + threadIdx.x;
  if (i < 5120) cnt[i] = 0;
}

// Pass 1: per pixel compute both gradient sets (per-channel to cap VGPRs),
// store as 3 float4 planes; segment count atomic returns within-segment rank
// (stored coalesced); 12-map min/max partials (2 px/thread, grid 2048 -> 8 blk/CU).
__global__ __launch_bounds__(256, 8) void k_mm(const float* __restrict__ img,
                                               const int* __restrict__ reg,
                                               int* __restrict__ cnt,
                                               int* __restrict__ rank,
                                               float4* __restrict__ grad4,
                                               float* __restrict__ pmin,
                                               float* __restrict__ pmax,
                                               float cb, float sb, float cf, float sf) {
  int tbase = blockIdx.x * 256 + threadIdx.x;   // [0, 524288)
  float vmn[12], vmx[12];
  #pragma unroll
  for (int m = 0; m < 12; ++m) { vmn[m] = FLT_MAX; vmx[m] = -FLT_MAX; }

  #pragma unroll
  for (int k = 0; k < 2; ++k) {
    int p = tbase + k * (NPIX / 2);
    int y = p >> 10, x = p & (WW - 1);
    int s = reg[p];
    if ((unsigned)s < (unsigned)NBSEG) rank[p] = atomicAdd(&cnt[s], 1);

    // ---- rot-tap geometry (shared across channels): 9 indices + validity mask
    float sx, sy;
    {
      #pragma clang fp contract(off)
      float dx = (float)(x + START) - 1024.5f;   // ncx of 2050-grid
      float dy = (float)(y + START) - 1024.5f;
      sx = cb*dx - sb*dy + 724.0f;               // cx of 1449-grid
      sy = sb*dx + cb*dy + 724.0f;
    }
    bool valid2 = (sx >= -0.5f) && (sx <= (float)RW - 0.5f) &&
                  (sy >= -0.5f) && (sy <= (float)RH - 0.5f);
    int ix = min(max((int)rintf(sx), 0), RW - 1);
    int iy = min(max((int)rintf(sy), 0), RH - 1);

    int idxs[9];
    unsigned okm = 0;
    #pragma unroll
    for (int t = 0; t < 9; ++t) {
      int rx = ix + (t % 3) - 1, ry = iy + (t / 3) - 1;
      bool inside = ((unsigned)rx < (unsigned)RW) && ((unsigned)ry < (unsigned)RH);
      float fx, fy;
      {
        #pragma clang fp contract(off)
        float ddx = (float)rx - 724.0f;   // ncx of 1449-grid
        float ddy = (float)ry - 724.0f;
        fx = cf*ddx - sf*ddy + 511.5f;    // cx of 1024-grid
        fy = sf*ddx + cf*ddy + 511.5f;
      }
      bool v1 = (fx >= -0.5f) && (fx <= 1023.5f) && (fy >= -0.5f) && (fy <= 1023.5f);
      int jx = min(max((int)rintf(fx), 0), WW - 1);
      int jy = min(max((int)rintf(fy), 0), HH - 1);
      idxs[t] = jy * WW + jx;
      okm |= ((unsigned)(inside && v1)) << t;
    }

    bool interior = (x >= 1) && (x <= WW - 2) && (y >= 1) && (y <= HH - 2);

    #pragma unroll
    for (int c = 0; c < 3; ++c) {
      const float* pp = img + (long)c * NPIX;
      float n00, n01, n02, n10, n12, n20, n21, n22;
      if (interior) {
        const float* q = pp + p;
        n00 = q[-WW - 1]; n01 = q[-WW]; n02 = q[-WW + 1];
        n10 = q[-1];                    n12 = q[1];
        n20 = q[WW - 1];  n21 = q[WW];  n22 = q[WW + 1];
      } else {
        bool yu = y > 0, yd = y < HH - 1, xl = x > 0, xr = x < WW - 1;
        n00 = (yu && xl) ? pp[p - WW - 1] : 0.0f;
        n01 = (yu)       ? pp[p - WW]     : 0.0f;
        n02 = (yu && xr) ? pp[p - WW + 1] : 0.0f;
        n10 = (xl)       ? pp[p - 1]      : 0.0f;
        n12 = (xr)       ? pp[p + 1]      : 0.0f;
        n20 = (yd && xl) ? pp[p + WW - 1] : 0.0f;
        n21 = (yd)       ? pp[p + WW]     : 0.0f;
        n22 = (yd && xr) ? pp[p + WW + 1] : 0.0f;
      }
      float a0 = -3.0f*n00 + 3.0f*n02 + 10.0f*n10 + 10.0f*n12 - 3.0f*n20 + 3.0f*n22;
      float a1 = -3.0f*n00 + 10.0f*n01 - 3.0f*n02 + 3.0f*n20 + 10.0f*n21 + 3.0f*n22;

      float m0, m1, m2, m3, m5, m6, m7, m8;
      m0 = (okm & 1u)   ? pp[idxs[0]] : 0.0f;
      m1 = (okm & 2u)   ? pp[idxs[1]] : 0.0f;
      m2 = (okm & 4u)   ? pp[idxs[2]] : 0.0f;
      m3 = (okm & 8u)   ? pp[idxs[3]] : 0.0f;
      m5 = (okm & 32u)  ? pp[idxs[5]] : 0.0f;
      m6 = (okm & 64u)  ? pp[idxs[6]] : 0.0f;
      m7 = (okm & 128u) ? pp[idxs[7]] : 0.0f;
      m8 = (okm & 256u) ? pp[idxs[8]] : 0.0f;
      float r0 = -3.0f*m0 + 3.0f*m2 + 10.0f*m3 + 10.0f*m5 - 3.0f*m6 + 3.0f*m8;
      float r1 = -3.0f*m0 + 10.0f*m1 - 3.0f*m2 + 3.0f*m6 + 10.0f*m7 + 3.0f*m8;
      float b0 = valid2 ? r0 : 0.0f;
      float b1 = valid2 ? r1 : 0.0f;

      grad4[(long)c * NPIX + p] = make_float4(a0, a1, b0, b1);

      vmn[2*c]     = fminf(vmn[2*c],     a0); vmx[2*c]     = fmaxf(vmx[2*c],     a0);
      vmn[2*c + 1] = fminf(vmn[2*c + 1], a1); vmx[2*c + 1] = fmaxf(vmx[2*c + 1], a1);
      vmn[6 + 2*c]     = fminf(vmn[6 + 2*c],     b0); vmx[6 + 2*c]     = fmaxf(vmx[6 + 2*c],     b0);
      vmn[6 + 2*c + 1] = fminf(vmn[6 + 2*c + 1], b1); vmx[6 + 2*c + 1] = fmaxf(vmx[6 + 2*c + 1], b1);
    }
  }

  #pragma unroll
  for (int off = 32; off >= 1; off >>= 1) {
    #pragma unroll
    for (int m = 0; m < 12; ++m) {
      vmn[m] = fminf(vmn[m], __shfl_xor(vmn[m], off));
      vmx[m] = fmaxf(vmx[m], __shfl_xor(vmx[m], off));
    }
  }
  __shared__ float smn[12][4], smx[12][4];
  int wv = threadIdx.x >> 6;
  if ((threadIdx.x & 63) == 0) {
    #pragma unroll
    for (int m = 0; m < 12; ++m) { smn[m][wv] = vmn[m]; smx[m][wv] = vmx[m]; }
  }
  __syncthreads();
  if (threadIdx.x < 12) {
    int m = threadIdx.x;
    float mn = fminf(fminf(smn[m][0], smn[m][1]), fminf(smn[m][2], smn[m][3]));
    float mx = fmaxf(fmaxf(smx[m][0], smx[m][1]), fmaxf(smx[m][2], smx[m][3]));
    pmin[m * NBLK_MM + blockIdx.x] = mn;
    pmax[m * NBLK_MM + blockIdx.x] = mx;
  }
}

// Fused: blocks 0..11 reduce one map's partials -> gmm; block 12 prefix-scans counts.
__global__ __launch_bounds__(1024) void k_redscan(const float* __restrict__ pmin,
                                                  const float* __restrict__ pmax,
                                                  const int* __restrict__ cnt,
                                                  float* __restrict__ gmm,
                                                  int* __restrict__ start) {
  int t = threadIdx.x;
  if (blockIdx.x < 12) {
    int m = blockIdx.x;
    float mn = fminf(pmin[m * NBLK_MM + t], pmin[m * NBLK_MM + 1024 + t]);
    float mx = fmaxf(pmax[m * NBLK_MM + t], pmax[m * NBLK_MM + 1024 + t]);
    #pragma unroll
    for (int off = 32; off >= 1; off >>= 1) {
      mn = fminf(mn, __shfl_xor(mn, off));
      mx = fmaxf(mx, __shfl_xor(mx, off));
    }
    __shared__ float smn[16], smx[16];
    int wv = t >> 6;
    if ((t & 63) == 0) { smn[wv] = mn; smx[wv] = mx; }
    __syncthreads();
    if (t == 0) {
      #pragma unroll
      for (int i = 1; i < 16; ++i) { mn = fminf(mn, smn[i]); mx = fmaxf(mx, smx[i]); }
      gmm[2*m] = mn; gmm[2*m + 1] = mx;
    }
    return;
  }
  // block 12: exclusive scan of 5000 counts
  __shared__ int part[1024];
  int base = t * 5;
  int v[5]; int sum = 0;
  #pragma unroll
  for (int j = 0; j < 5; ++j) {
    v[j] = (base + j < NBSEG) ? cnt[base + j] : 0;
    sum += v[j];
  }
  part[t] = sum;
  __syncthreads();
  #pragma unroll
  for (int d = 1; d < 1024; d <<= 1) {
    int xv = (t >= d) ? part[t - d] : 0;
    __syncthreads();
    part[t] += xv;
    __syncthreads();
  }
  int run = (t > 0) ? part[t - 1] : 0;   // exclusive
  #pragma unroll
  for (int j = 0; j < 5; ++j) {
    int i = base + j;
    if (i <= NBSEG) start[i] = run;
    run += v[j];
  }
}

// Scatter pixel index to its sorted-by-segment position (no atomics: rank from k_mm).
__global__ __launch_bounds__(256) void k_perm(const int* __restrict__ reg,
                                              const int* __restrict__ rank,
                                              const int* __restrict__ start,
                                              int* __restrict__ perm) {
  int p = blockIdx.x * 256 + threadIdx.x;
  int s = reg[p];
  if ((unsigned)s < (unsigned)NBSEG) perm[start[s] + rank[p]] = p;
}

// One block per segment: gather grads, quantize (bit-identical to reference),
// ballot-popcount histograms (5 LDS atomics per wave instead of 27 per record),
// shuffle-reduced bbox, fused normalization, single write.
__global__ __launch_bounds__(256) void k_accum(const int* __restrict__ perm,
                                               const int* __restrict__ start,
                                               const float4* __restrict__ grad4,
                                               const float* __restrict__ img,
                                               const float* __restrict__ gmm,
                                               float* __restrict__ out) {
  __shared__ float params[48];
  __shared__ unsigned hist[316];
  __shared__ int bb[4];
  int tid = threadIdx.x;
  int lane = tid & 63;

  if (tid < 24) {
    int t = tid;
    int c = t / 8, k = t % 8;
    int b = (k < 4) ? (2*c + (k & 1)) : (6 + 2*c + (k & 1));
    bool pos = ((k >> 1) & 1) == 0;   // k in {0,1,4,5} -> max(.,0); {2,3,6,7} -> min(.,0)
    float mn = gmm[2*b], mx = gmm[2*b + 1];
    float hmin, hmax;
    if (pos) { hmin = fmaxf(mn, 0.0f); hmax = fmaxf(mx, 0.0f); }
    else     { hmin = fminf(mn, 0.0f); hmax = fminf(mx, 0.0f); }
    params[2*t]     = hmin;
    params[2*t + 1] = hmax - hmin;
  }
  for (int i = tid; i < 316; i += 256) hist[i] = 0;
  if (tid == 0) { bb[0] = INT_MAX; bb[1] = INT_MAX; bb[2] = INT_MIN; bb[3] = INT_MIN; }
  __syncthreads();

  int s = blockIdx.x;
  int beg = start[s], end = start[s + 1];
  int n = end - beg;

  unsigned acc[5] = {0, 0, 0, 0, 0};   // lane-sliced: acc[j] counts bin (64*j + lane)
  int xmn = INT_MAX, ymn = INT_MAX, xmx = INT_MIN, ymx = INT_MIN;

  for (int base2 = beg; base2 < end; base2 += 256) {
    int i = base2 + tid;
    bool act = i < end;
    int p = act ? perm[i] : 0;

    unsigned qv[24];
    unsigned qc[3];
    #pragma unroll
    for (int c = 0; c < 3; ++c) {
      float4 g = grad4[(long)c * NPIX + p];
      float gv[2] = { g.x, g.y };
      float rv[2] = { g.z, g.w };
      #pragma unroll
      for (int d = 0; d < 2; ++d) {
        {
          int m = c*8 + d;
          float v = fmaxf(gv[d], 0.0f);
          int qq = (int)(((v - params[2*m]) / params[2*m + 1]) * 9.0f);
          qv[m] = act ? (unsigned)min(max(qq, 0), 9) : 0xFFu;
        }
        {
          int m = c*8 + 2 + d;
          float v = fminf(gv[d], 0.0f);
          int qq = (int)(((v - params[2*m]) / params[2*m + 1]) * 9.0f);
          qv[m] = act ? (unsigned)min(max(qq, 0), 9) : 0xFFu;
        }
        {
          int m = c*8 + 4 + d;
          float v = fmaxf(rv[d], 0.0f);
          int qq = (int)(((v - params[2*m]) / params[2*m + 1]) * 9.0f);
          qv[m] = act ? (unsigned)min(max(qq, 0), 9) : 0xFFu;
        }
        {
          int m = c*8 + 6 + d;
          float v = fminf(rv[d], 0.0f);
          int qq = (int)(((v - params[2*m]) / params[2*m + 1]) * 9.0f);
          qv[m] = act ? (unsigned)min(max(qq, 0), 9) : 0xFFu;
        }
      }
      int cc = (int)(img[(long)c * NPIX + p] * 24.0f);   // (img*(cb-1)).astype(int32)
      qc[c] = act ? (unsigned)min(max(cc, 0), 24) : 0xFFu;
    }

    if (act) {
      int x = p & 1023, y = p >> 10;
      xmn = min(xmn, x); ymn = min(ymn, y);
      xmx = max(xmx, x); ymx = max(ymx, y);
    }

    // ballot histograms: one uniform popcount per (map,bin), lane-sliced accumulate
    #pragma unroll
    for (int m = 0; m < 24; ++m) {
      #pragma unroll
      for (int b = 0; b < 10; ++b) {
        unsigned cntb = (unsigned)__popcll(__ballot(qv[m] == (unsigned)b));
        int idx = m * 10 + b;
        acc[idx >> 6] += (lane == (idx & 63)) ? cntb : 0u;
      }
    }
    #pragma unroll
    for (int cm = 0; cm < 3; ++cm) {
      #pragma unroll
      for (int b = 0; b < 25; ++b) {
        unsigned cntb = (unsigned)__popcll(__ballot(qc[cm] == (unsigned)b));
        int idx = 240 + cm * 25 + b;
        acc[idx >> 6] += (lane == (idx & 63)) ? cntb : 0u;
      }
    }
  }

  // flush lane-sliced counters (5 LDS atomics per wave)
  #pragma unroll
  for (int j = 0; j < 5; ++j) {
    int idx = j * 64 + lane;
    if (idx < 315 && acc[j]) atomicAdd(&hist[idx], acc[j]);
  }

  // bbox: wave shuffle-reduce, then one LDS atomic set per wave
  #pragma unroll
  for (int off = 32; off >= 1; off >>= 1) {
    xmn = min(xmn, __shfl_xor(xmn, off));
    ymn = min(ymn, __shfl_xor(ymn, off));
    xmx = max(xmx, __shfl_xor(xmx, off));
    ymx = max(ymx, __shfl_xor(ymx, off));
  }
  if (lane == 0) {
    atomicMin(&bb[0], xmn); atomicMin(&bb[1], ymn);
    atomicMax(&bb[2], xmx); atomicMax(&bb[3], ymx);
  }
  __syncthreads();

  if (tid == 0) {
    out[4*s + 0] = (float)bb[0];
    out[4*s + 1] = (float)bb[1];
    out[4*s + 2] = (float)(bb[2] - bb[0]);
    out[4*s + 3] = (float)(bb[3] - bb[1]);
    out[OUT_SIZE_OFF + s] = (float)n;
  }
  bool ok = n > 0;
  float cden = 3.0f * (float)n, tden = 24.0f * (float)n;
  for (int i = tid; i < 240; i += 256)
    out[OUT_TEX_OFF + s*240 + i] = ok ? (float)hist[i] / tden : 0.0f;
  for (int i = tid; i < 75; i += 256)
    out[OUT_COLOR_OFF + s*75 + i] = ok ? (float)hist[240 + i] / cden : 0.0f;
}

// ---------------- launch ----------------

extern "C" void kernel_launch(void* const* d_in, const int* in_sizes, int n_in,
                              void* d_out, int out_size, void* d_ws, size_t ws_size,
                              hipStream_t stream) {
  const float* img = (const float*)d_in[0];
  const int*   reg = (const int*)d_in[1];
  float* out = (float*)d_out;

  char* ws = (char*)d_ws;
  size_t off = 0;
  float4* grad4 = (float4*)(ws + off); off += (size_t)3 * NPIX * 16;  off = (off + 255) & ~(size_t)255;
  int*    rank  = (int*)(ws + off);    off += (size_t)NPIX * 4;       off = (off + 255) & ~(size_t)255;
  int*    perm  = (int*)(ws + off);    off += (size_t)NPIX * 4;       off = (off + 255) & ~(size_t)255;
  int*    cnt   = (int*)(ws + off);    off += 5120 * 4;
  int*    start = (int*)(ws + off);    off += 5008 * 4;
  float*  gmm   = (float*)(ws + off);  off += 32 * 4;                 off = (off + 255) & ~(size_t)255;
  float*  pmin  = (float*)(ws + off);  off += (size_t)12 * NBLK_MM * 4;
  float*  pmax  = (float*)(ws + off);  off += (size_t)12 * NBLK_MM * 4;
  (void)ws_size; (void)in_sizes; (void)n_in; (void)out_size;

  double th  = 45.0 * (M_PI / 180.0);
  float cf = (float)cos(th),  sf = (float)sin(th);    // forward +45
  double thb = -45.0 * (M_PI / 180.0);
  float cbk = (float)cos(thb), sbk = (float)sin(thb); // backward -45

  k_zero   <<<20,        256,  0, stream>>>(cnt);
  k_mm     <<<NBLK_MM,   256,  0, stream>>>(img, reg, cnt, rank, grad4, pmin, pmax, cbk, sbk, cf, sf);
  k_redscan<<<13,        1024, 0, stream>>>(pmin, pmax, cnt, gmm, start);
  k_perm   <<<NPIX/256,  256,  0, stream>>>(reg, rank, start, perm);
  k_accum  <<<NBSEG,     256,  0, stream>>>(perm, start, grad4, img, gmm, out);
}